// Round 7
// baseline (138.092 us; speedup 1.0000x reference)
//
#include <hip/hip_runtime.h>
#include <hip/hip_bf16.h>

// SequenceReductionAttention (PVT-style SRA).
// B=4, N=4096 (64x64), C=256, heads=8, d=32, SR=2 -> N'=1024 (32x32).
//
// Round 7: revert attn main loop to round-5 (verified 57us) structure;
// fuse the q GEMM into the attention prologue (per-wave Q^T = mfma(qw, x)
// over K=256, fixed up into B-frags via cvt_pk + permlane32_swap with
// qscale folded). x cast fused into conv staging. cast_bf16 / q-gemm /
// x_bf / q_bf all deleted.

typedef __attribute__((ext_vector_type(8))) short bf16x8;
typedef __attribute__((ext_vector_type(8))) unsigned short u16x8;
typedef __attribute__((ext_vector_type(4))) float f32x4;
typedef __attribute__((ext_vector_type(16))) float f32x16;
typedef __attribute__((ext_vector_type(2))) unsigned u32x2v;
typedef __attribute__((ext_vector_type(4))) unsigned u32x4v;

__device__ inline unsigned short f2bf(float f) {
  unsigned u = __float_as_uint(f);
  u += 0x7fffu + ((u >> 16) & 1u);
  return (unsigned short)(u >> 16);
}

// ---------------------------------------------------------------------------
// sr_w [256 o][256 ci][4 tap] fp32 -> srw_bf [256 o][4 tap][256 ci] bf16.
__global__ __launch_bounds__(256) void perm_srw(
    const float* __restrict__ w, unsigned short* __restrict__ wp) {
  int o = blockIdx.x, t = threadIdx.x;
  float4 v = reinterpret_cast<const float4*>(w + (size_t)o * 1024)[t];
  wp[(size_t)o * 1024 + 0 * 256 + t] = f2bf(v.x);
  wp[(size_t)o * 1024 + 1 * 256 + t] = f2bf(v.y);
  wp[(size_t)o * 1024 + 2 * 256 + t] = f2bf(v.z);
  wp[(size_t)o * 1024 + 3 * 256 + t] = f2bf(v.w);
}

// ---------------------------------------------------------------------------
// MFMA GEMM: C[M,N] = (A[M,K](bf16) @ W[N,K](f32->bf16)^T) * oscale (+bias).
// Block 128x64, BK=32, 4 waves (each 64x32).
template <bool BF16_OUT, bool HAS_BIAS>
__global__ __launch_bounds__(256) void mfma_gemm(
    const unsigned short* __restrict__ A, const float* __restrict__ W,
    const float* __restrict__ bias, void* __restrict__ Cv,
    int M, int N, int K, float oscale) {
  __shared__ unsigned short Asb[128 * 40];
  __shared__ unsigned short Bsb[64 * 40];
  const int tid = threadIdx.x;
  const int w = tid >> 6, l = tid & 63, c = l & 15, g = l >> 4;
  const int wr = w >> 1, wc = w & 1;
  const int m0 = blockIdx.y * 128, n0 = blockIdx.x * 64;
  const int ar = tid >> 1, ah = tid & 1;
  const int bn = tid >> 2, bq = tid & 3;

  f32x4 acc[4][2];
#pragma unroll
  for (int mt = 0; mt < 4; ++mt)
#pragma unroll
    for (int nt = 0; nt < 2; ++nt)
#pragma unroll
      for (int r = 0; r < 4; ++r) acc[mt][nt][r] = 0.f;

  for (int k0 = 0; k0 < K; k0 += 32) {
    __syncthreads();
    {
      const unsigned short* asrc = A + (size_t)(m0 + ar) * K + k0 + ah * 16;
      u16x8 a0 = *reinterpret_cast<const u16x8*>(asrc);
      u16x8 a1 = *reinterpret_cast<const u16x8*>(asrc + 8);
      *reinterpret_cast<u16x8*>(&Asb[ar * 40 + ah * 16]) = a0;
      *reinterpret_cast<u16x8*>(&Asb[ar * 40 + ah * 16 + 8]) = a1;
    }
    {
      const float* wsrc = W + (size_t)(n0 + bn) * K + k0 + bq * 8;
      float4 w0 = *reinterpret_cast<const float4*>(wsrc);
      float4 w1 = *reinterpret_cast<const float4*>(wsrc + 4);
      u16x8 wb;
      wb[0] = f2bf(w0.x); wb[1] = f2bf(w0.y); wb[2] = f2bf(w0.z); wb[3] = f2bf(w0.w);
      wb[4] = f2bf(w1.x); wb[5] = f2bf(w1.y); wb[6] = f2bf(w1.z); wb[7] = f2bf(w1.w);
      *reinterpret_cast<u16x8*>(&Bsb[bn * 40 + bq * 8]) = wb;
    }
    __syncthreads();
    bf16x8 af[4], bfr[2];
#pragma unroll
    for (int mt = 0; mt < 4; ++mt)
      af[mt] = *reinterpret_cast<const bf16x8*>(
          &Asb[(wr * 64 + mt * 16 + c) * 40 + g * 8]);
#pragma unroll
    for (int nt = 0; nt < 2; ++nt)
      bfr[nt] = *reinterpret_cast<const bf16x8*>(
          &Bsb[(wc * 32 + nt * 16 + c) * 40 + g * 8]);
#pragma unroll
    for (int mt = 0; mt < 4; ++mt)
#pragma unroll
      for (int nt = 0; nt < 2; ++nt)
        acc[mt][nt] = __builtin_amdgcn_mfma_f32_16x16x32_bf16(
            af[mt], bfr[nt], acc[mt][nt], 0, 0, 0);
  }

#pragma unroll
  for (int mt = 0; mt < 4; ++mt)
#pragma unroll
    for (int nt = 0; nt < 2; ++nt) {
      int row = m0 + wr * 64 + mt * 16 + g * 4;
      int col = n0 + wc * 32 + nt * 16 + c;
      float bv = HAS_BIAS ? bias[col] : 0.f;
#pragma unroll
      for (int r = 0; r < 4; ++r) {
        float v = acc[mt][nt][r] * oscale + bv;
        if (BF16_OUT)
          ((unsigned short*)Cv)[(size_t)(row + r) * N + col] = f2bf(v);
        else
          ((float*)Cv)[(size_t)(row + r) * N + col] = v;
      }
    }
}

// ---------------------------------------------------------------------------
// Conv(k=2,s=2) as MFMA GEMM with tap-major K; A gathered from x (f32,
// cast on stage). Block 64x64, 4 waves (32x32).
__global__ __launch_bounds__(256) void conv_mfma(
    const float* __restrict__ X, const unsigned short* __restrict__ Wp,
    const float* __restrict__ bias, float* __restrict__ C) {
  __shared__ unsigned short Asb[64 * 40];
  __shared__ unsigned short Bsb[64 * 40];
  const int tid = threadIdx.x;
  const int w = tid >> 6, l = tid & 63, c = l & 15, g = l >> 4;
  const int wr = w >> 1, wc = w & 1;
  const int m0 = blockIdx.y * 64, n0 = blockIdx.x * 64;
  const int sr = tid >> 2, sh = tid & 3;

  int base[4];
  {
    int row = m0 + sr;
    int b = row >> 10, o = row & 1023, oh = o >> 5, ow = o & 31;
#pragma unroll
    for (int tap = 0; tap < 4; ++tap) {
      int n = ((oh << 1) + (tap >> 1)) * 64 + (ow << 1) + (tap & 1);
      base[tap] = ((b << 12) + n) << 8;
    }
  }

  f32x4 acc[2][2];
#pragma unroll
  for (int mt = 0; mt < 2; ++mt)
#pragma unroll
    for (int nt = 0; nt < 2; ++nt)
#pragma unroll
      for (int r = 0; r < 4; ++r) acc[mt][nt][r] = 0.f;

  for (int k0 = 0; k0 < 1024; k0 += 32) {
    const int tap = k0 >> 8, ci0 = (k0 & 255) + sh * 8;
    __syncthreads();
    {
      const float* xp = X + base[tap] + ci0;
      float4 a0 = *reinterpret_cast<const float4*>(xp);
      float4 a1 = *reinterpret_cast<const float4*>(xp + 4);
      u16x8 av;
      av[0] = f2bf(a0.x); av[1] = f2bf(a0.y); av[2] = f2bf(a0.z); av[3] = f2bf(a0.w);
      av[4] = f2bf(a1.x); av[5] = f2bf(a1.y); av[6] = f2bf(a1.z); av[7] = f2bf(a1.w);
      *reinterpret_cast<u16x8*>(&Asb[sr * 40 + sh * 8]) = av;
    }
    u16x8 wv = *reinterpret_cast<const u16x8*>(
        &Wp[(size_t)(n0 + sr) * 1024 + k0 + sh * 8]);
    *reinterpret_cast<u16x8*>(&Bsb[sr * 40 + sh * 8]) = wv;
    __syncthreads();
    bf16x8 af[2], bfr[2];
#pragma unroll
    for (int mt = 0; mt < 2; ++mt)
      af[mt] = *reinterpret_cast<const bf16x8*>(
          &Asb[(wr * 32 + mt * 16 + c) * 40 + g * 8]);
#pragma unroll
    for (int nt = 0; nt < 2; ++nt)
      bfr[nt] = *reinterpret_cast<const bf16x8*>(
          &Bsb[(wc * 32 + nt * 16 + c) * 40 + g * 8]);
#pragma unroll
    for (int mt = 0; mt < 2; ++mt)
#pragma unroll
      for (int nt = 0; nt < 2; ++nt)
        acc[mt][nt] = __builtin_amdgcn_mfma_f32_16x16x32_bf16(
            af[mt], bfr[nt], acc[mt][nt], 0, 0, 0);
  }

#pragma unroll
  for (int mt = 0; mt < 2; ++mt)
#pragma unroll
    for (int nt = 0; nt < 2; ++nt) {
      int row = m0 + wr * 32 + mt * 16 + g * 4;
      int col = n0 + wc * 32 + nt * 16 + c;
      float bv = bias[col];
#pragma unroll
      for (int r = 0; r < 4; ++r)
        C[(size_t)(row + r) * 256 + col] = acc[mt][nt][r] + bv;
    }
}

// ---------------------------------------------------------------------------
// LayerNorm over C=256; f32 in, bf16 out.
__global__ __launch_bounds__(256) void ln_kernel(
    const float* __restrict__ xr, const float* __restrict__ gam,
    const float* __restrict__ bet, unsigned short* __restrict__ xo) {
  const int row = blockIdx.x;
  const int t = threadIdx.x;
  float v = xr[(size_t)row * 256 + t];
  float s = v, s2 = v * v;
#pragma unroll
  for (int off = 32; off > 0; off >>= 1) {
    s  += __shfl_down(s, off, 64);
    s2 += __shfl_down(s2, off, 64);
  }
  __shared__ float red[8];
  const int wid = t >> 6;
  if ((t & 63) == 0) { red[wid] = s; red[wid + 4] = s2; }
  __syncthreads();
  s  = red[0] + red[1] + red[2] + red[3];
  s2 = red[4] + red[5] + red[6] + red[7];
  float mean = s * (1.f / 256.f);
  float var = s2 * (1.f / 256.f) - mean * mean;
  float rstd = rsqrtf(var + 1e-5f);
  xo[(size_t)row * 256 + t] = f2bf((v - mean) * rstd * gam[t] + bet[t]);
}

// ---------------------------------------------------------------------------
// 32x32x16-MFMA flash attention with FUSED q projection.
// Block = 2 waves, 64 q rows (32/wave). KV step = 64 (2 kv-blocks of 32).
// Prologue: Q^T[32d][32q] = mfma(qw_head rows, x rows) over K=256, then
// fixup to B-frags (cvt_pk + permlane32_swap), qscale*log2e folded.
// Main loop identical to the round-5 verified kernel.
__global__ __launch_bounds__(128) void attn_mfma(
    const float* __restrict__ X, const float* __restrict__ QW,
    const unsigned short* __restrict__ KVb,
    unsigned short* __restrict__ O) {
  __shared__ __align__(16) unsigned short Vt[2][32][72];  // V^T dbuf, padded

  const int tid = threadIdx.x;
  const int l = tid & 63;
  const int w = tid >> 6;
  const int q32 = l & 31;
  const int hi = l >> 5;
  const int wg = blockIdx.x;
  const int qb = wg & 63, head = (wg >> 6) & 7, b = wg >> 9;
  const int hcol = head << 5;
  const int q0 = (b << 12) + (qb << 6) + (w << 5);
  const int kvrow0 = b << 10;

  // V staging mapping: 128 threads cover 32 kv-pairs x 4 d-chunks.
  const int pairidx = tid & 31;
  const int dchunk = tid >> 5;
  const int kv0 = pairidx * 2;

  // prologue part 1: stage V^T for tile 0 into buf 0 (issue loads early)
  {
    const unsigned short* vp =
        KVb + (size_t)(kvrow0 + kv0) * 512 + 256 + hcol + dchunk * 8;
    u16x8 v0 = *reinterpret_cast<const u16x8*>(vp);
    u16x8 v1 = *reinterpret_cast<const u16x8*>(vp + 512);
#pragma unroll
    for (int j = 0; j < 8; ++j)
      *reinterpret_cast<unsigned*>(&Vt[0][dchunk * 8 + j][kv0]) =
          (unsigned)(unsigned short)v0[j] |
          ((unsigned)(unsigned short)v1[j] << 16);
  }

  // prologue part 2: compute Q^T = qw_head @ x^T over K=256 (16 MFMAs)
  bf16x8 qf[2];
  {
    const float* wrow = QW + (size_t)(hcol + q32) * 256 + hi * 8;  // A: d-rows
    const float* xrow = X + (size_t)(q0 + q32) * 256 + hi * 8;     // B: q-rows
    f32x16 qacc;
#pragma unroll
    for (int r = 0; r < 16; ++r) qacc[r] = 0.f;
#pragma unroll
    for (int kk = 0; kk < 16; ++kk) {
      const float* wp = wrow + kk * 16;
      const float* xp = xrow + kk * 16;
      float4 w0 = *reinterpret_cast<const float4*>(wp);
      float4 w1 = *reinterpret_cast<const float4*>(wp + 4);
      float4 x0 = *reinterpret_cast<const float4*>(xp);
      float4 x1 = *reinterpret_cast<const float4*>(xp + 4);
      u16x8 afu, bfu;
      afu[0] = f2bf(w0.x); afu[1] = f2bf(w0.y); afu[2] = f2bf(w0.z); afu[3] = f2bf(w0.w);
      afu[4] = f2bf(w1.x); afu[5] = f2bf(w1.y); afu[6] = f2bf(w1.z); afu[7] = f2bf(w1.w);
      bfu[0] = f2bf(x0.x); bfu[1] = f2bf(x0.y); bfu[2] = f2bf(x0.z); bfu[3] = f2bf(x0.w);
      bfu[4] = f2bf(x1.x); bfu[5] = f2bf(x1.y); bfu[6] = f2bf(x1.z); bfu[7] = f2bf(x1.w);
      qacc = __builtin_amdgcn_mfma_f32_32x32x16_bf16(
          __builtin_bit_cast(bf16x8, afu), __builtin_bit_cast(bf16x8, bfu),
          qacc, 0, 0, 0);
    }
    // fixup: C layout (lane q, d-rows (r&3)+8*(r>>2)+4*hi) -> B-frags
    // (lane q, d = hi*8+j / 16+hi*8+j), qscale folded.
    const float qs = 0.25506975154985854f;  // (1/sqrt(32)) * log2(e)
    unsigned QA[8];
#pragma unroll
    for (int i = 0; i < 8; ++i) {
      float p0 = qacc[2 * i] * qs, p1 = qacc[2 * i + 1] * qs;
      unsigned o;
      asm("v_cvt_pk_bf16_f32 %0, %1, %2" : "=v"(o) : "v"(p0), "v"(p1));
      QA[i] = o;
    }
    u32x2v q02 = __builtin_amdgcn_permlane32_swap(QA[0], QA[2], false, false);
    u32x2v q13 = __builtin_amdgcn_permlane32_swap(QA[1], QA[3], false, false);
    u32x2v q46 = __builtin_amdgcn_permlane32_swap(QA[4], QA[6], false, false);
    u32x2v q57 = __builtin_amdgcn_permlane32_swap(QA[5], QA[7], false, false);
    u32x4v pk0 = {q02[0], q13[0], q02[1], q13[1]};
    u32x4v pk1 = {q46[0], q57[0], q46[1], q57[1]};
    qf[0] = __builtin_bit_cast(bf16x8, pk0);
    qf[1] = __builtin_bit_cast(bf16x8, pk1);
  }

  f32x16 acc;
#pragma unroll
  for (int r = 0; r < 16; ++r) acc[r] = 0.f;
  float lsum = 0.f;

  for (int t = 0; t < 16; ++t) {
    const int cur = t & 1;
    __syncthreads();

    // prefetch next V tile into regs (latency hides under QK+softmax)
    u16x8 nv0, nv1;
    if (t < 15) {
      const unsigned short* vp =
          KVb + (size_t)(kvrow0 + (t + 1) * 64 + kv0) * 512 + 256 + hcol + dchunk * 8;
      nv0 = *reinterpret_cast<const u16x8*>(vp);
      nv1 = *reinterpret_cast<const u16x8*>(vp + 512);
    }

    // ---- QK^T (swapped): S^T[kv][q] = mfma32(K, Q) ----
    const unsigned short* kbase =
        KVb + (size_t)(kvrow0 + t * 64 + q32) * 512 + hcol + hi * 8;
    f32x16 s[2];
    {
      bf16x8 k00 = *reinterpret_cast<const bf16x8*>(kbase);
      bf16x8 k01 = *reinterpret_cast<const bf16x8*>(kbase + 16);
      bf16x8 k10 = *reinterpret_cast<const bf16x8*>(kbase + 32 * 512);
      bf16x8 k11 = *reinterpret_cast<const bf16x8*>(kbase + 32 * 512 + 16);
      f32x16 z;
#pragma unroll
      for (int r = 0; r < 16; ++r) z[r] = 0.f;
      s[0] = __builtin_amdgcn_mfma_f32_32x32x16_bf16(k00, qf[0], z, 0, 0, 0);
      s[0] = __builtin_amdgcn_mfma_f32_32x32x16_bf16(k01, qf[1], s[0], 0, 0, 0);
      s[1] = __builtin_amdgcn_mfma_f32_32x32x16_bf16(k10, qf[0], z, 0, 0, 0);
      s[1] = __builtin_amdgcn_mfma_f32_32x32x16_bf16(k11, qf[1], s[1], 0, 0, 0);
    }

    // ---- softmax + in-register P redistribution + PV ----
#pragma unroll
    for (int kvb = 0; kvb < 2; ++kvb) {
      float p[16];
#pragma unroll
      for (int r = 0; r < 16; ++r) {
        p[r] = __builtin_amdgcn_exp2f(s[kvb][r]);
        lsum += p[r];
      }
      unsigned A[8];
#pragma unroll
      for (int i = 0; i < 8; ++i) {
        unsigned o;
        asm("v_cvt_pk_bf16_f32 %0, %1, %2"
            : "=v"(o) : "v"(p[2 * i]), "v"(p[2 * i + 1]));
        A[i] = o;
      }
      u32x2v r02 = __builtin_amdgcn_permlane32_swap(A[0], A[2], false, false);
      u32x2v r13 = __builtin_amdgcn_permlane32_swap(A[1], A[3], false, false);
      u32x2v r46 = __builtin_amdgcn_permlane32_swap(A[4], A[6], false, false);
      u32x2v r57 = __builtin_amdgcn_permlane32_swap(A[5], A[7], false, false);
      u32x4v pk0 = {r02[0], r13[0], r02[1], r13[1]};
      u32x4v pk1 = {r46[0], r57[0], r46[1], r57[1]};
      bf16x8 pf0 = __builtin_bit_cast(bf16x8, pk0);
      bf16x8 pf1 = __builtin_bit_cast(bf16x8, pk1);
      const unsigned short* vrow = &Vt[cur][q32][kvb * 32 + hi * 8];
      bf16x8 vf0 = *reinterpret_cast<const bf16x8*>(vrow);
      bf16x8 vf1 = *reinterpret_cast<const bf16x8*>(vrow + 16);
      acc = __builtin_amdgcn_mfma_f32_32x32x16_bf16(vf0, pf0, acc, 0, 0, 0);
      acc = __builtin_amdgcn_mfma_f32_32x32x16_bf16(vf1, pf1, acc, 0, 0, 0);
    }

    // ---- write prefetched V into the other buffer ----
    if (t < 15) {
#pragma unroll
      for (int j = 0; j < 8; ++j)
        *reinterpret_cast<unsigned*>(&Vt[cur ^ 1][dchunk * 8 + j][kv0]) =
            (unsigned)(unsigned short)nv0[j] |
            ((unsigned)(unsigned short)nv1[j] << 16);
    }
  }

  // ---- epilogue: O^T[d][q] regs -> O[q][d] bf16 ----
  lsum += __shfl_xor(lsum, 32, 64);
  float inv = 1.f / lsum;
  unsigned short* orow = O + (size_t)(q0 + q32) * 256 + hcol;
#pragma unroll
  for (int rb = 0; rb < 4; ++rb) {
    const int d0 = rb * 8 + hi * 4;
    float a0 = acc[rb * 4 + 0] * inv, a1 = acc[rb * 4 + 1] * inv;
    float a2 = acc[rb * 4 + 2] * inv, a3 = acc[rb * 4 + 3] * inv;
    unsigned w0, w1;
    asm("v_cvt_pk_bf16_f32 %0, %1, %2" : "=v"(w0) : "v"(a0), "v"(a1));
    asm("v_cvt_pk_bf16_f32 %0, %1, %2" : "=v"(w1) : "v"(a2), "v"(a3));
    unsigned long long pk = (unsigned long long)w0 | ((unsigned long long)w1 << 32);
    *reinterpret_cast<unsigned long long*>(orow + d0) = pk;
  }
}

// ---------------------------------------------------------------------------
extern "C" void kernel_launch(void* const* d_in, const int* in_sizes, int n_in,
                              void* d_out, int out_size, void* d_ws,
                              size_t ws_size, hipStream_t stream) {
  const float* x      = (const float*)d_in[0];
  const float* sr_w   = (const float*)d_in[3];
  const float* sr_b   = (const float*)d_in[4];
  const float* ln_g   = (const float*)d_in[5];
  const float* ln_b   = (const float*)d_in[6];
  const float* q_w    = (const float*)d_in[7];
  const float* kv_w   = (const float*)d_in[8];
  const float* proj_w = (const float*)d_in[9];
  const float* proj_b = (const float*)d_in[10];
  float* out = (float*)d_out;

  char* ws = (char*)d_ws;
  unsigned short* srw_bf  = (unsigned short*)(ws);               // 512 KB
  float*          xred    = (float*)(ws + 524288);               // 4 MB
  unsigned short* x_ln    = (unsigned short*)(ws + 4718592);     // 2 MB
  unsigned short* kv_bf   = (unsigned short*)(ws + 6815744);     // 4 MB
  unsigned short* attn_bf = (unsigned short*)(ws + 11010048);    // 8 MB

  // 0. weight permute (f32 -> bf16 tap-major)
  perm_srw<<<256, 256, 0, stream>>>(sr_w, srw_bf);
  // 1. conv(k=2,s=2) + bias (f32 out), x cast fused into staging
  conv_mfma<<<dim3(4, 64), 256, 0, stream>>>(x, srw_bf, sr_b, xred);
  // 2. LayerNorm (bf16 out)
  ln_kernel<<<4096, 256, 0, stream>>>(xred, ln_g, ln_b, x_ln);
  // 3. kv = x_ln @ kv_w^T (bf16, interleaved [4096][512])
  mfma_gemm<true, false><<<dim3(8, 32), 256, 0, stream>>>(
      x_ln, kv_w, nullptr, kv_bf, 4096, 512, 256, 1.0f);
  // 4. attention with fused q projection (bf16 out)
  attn_mfma<<<2048, 128, 0, stream>>>(x, q_w, kv_bf, attn_bf);
  // 5. out = attn_o @ proj_w^T + proj_b (f32)
  mfma_gemm<false, true><<<dim3(4, 128), 256, 0, stream>>>(
      attn_bf, proj_w, proj_b, out, 16384, 256, 256, 1.0f);
}

// Round 8
// 127.672 us; speedup vs baseline: 1.0816x; 1.0816x over previous
//
#include <hip/hip_runtime.h>
#include <hip/hip_bf16.h>

// SequenceReductionAttention (PVT-style SRA).
// B=4, N=4096 (64x64), C=256, heads=8, d=32, SR=2 -> N'=1024 (32x32).
//
// Round 8: attention with NO LDS / NO barriers: 1 wave per block owns
// 32 q rows x full KV; K from k_buf [4096][256], V^T from vt_buf
// [(b*8+h)*32+d][1024] (both written by the kv GEMM). In-register softmax
// (cvt_pk + permlane32_swap), flat sum, Q pre-scaled. (b,head) in low
// blockIdx bits for per-XCD L2 KV locality.

typedef __attribute__((ext_vector_type(8))) short bf16x8;
typedef __attribute__((ext_vector_type(8))) unsigned short u16x8;
typedef __attribute__((ext_vector_type(4))) float f32x4;
typedef __attribute__((ext_vector_type(16))) float f32x16;
typedef __attribute__((ext_vector_type(2))) unsigned u32x2v;
typedef __attribute__((ext_vector_type(4))) unsigned u32x4v;

__device__ inline unsigned short f2bf(float f) {
  unsigned u = __float_as_uint(f);
  u += 0x7fffu + ((u >> 16) & 1u);
  return (unsigned short)(u >> 16);
}

// ---------------------------------------------------------------------------
// fp32 -> bf16 cast, 8 elems/thread.
__global__ __launch_bounds__(256) void cast_bf16(
    const float* __restrict__ in, unsigned short* __restrict__ out, int n8) {
  int i = blockIdx.x * 256 + threadIdx.x;
  if (i >= n8) return;
  float4 a = reinterpret_cast<const float4*>(in)[i * 2];
  float4 b = reinterpret_cast<const float4*>(in)[i * 2 + 1];
  ushort4 lo, hi;
  lo.x = f2bf(a.x); lo.y = f2bf(a.y); lo.z = f2bf(a.z); lo.w = f2bf(a.w);
  hi.x = f2bf(b.x); hi.y = f2bf(b.y); hi.z = f2bf(b.z); hi.w = f2bf(b.w);
  reinterpret_cast<ushort4*>(out)[i * 2] = lo;
  reinterpret_cast<ushort4*>(out)[i * 2 + 1] = hi;
}

// ---------------------------------------------------------------------------
// sr_w [256 o][256 ci][4 tap] fp32 -> srw_bf [256 o][4 tap][256 ci] bf16.
__global__ __launch_bounds__(256) void perm_srw(
    const float* __restrict__ w, unsigned short* __restrict__ wp) {
  int o = blockIdx.x, t = threadIdx.x;
  float4 v = reinterpret_cast<const float4*>(w + (size_t)o * 1024)[t];
  wp[(size_t)o * 1024 + 0 * 256 + t] = f2bf(v.x);
  wp[(size_t)o * 1024 + 1 * 256 + t] = f2bf(v.y);
  wp[(size_t)o * 1024 + 2 * 256 + t] = f2bf(v.z);
  wp[(size_t)o * 1024 + 3 * 256 + t] = f2bf(v.w);
}

// ---------------------------------------------------------------------------
// MFMA GEMM: C = (A[M,K](bf16) @ W[N,K](f32->bf16)^T) * oscale (+bias).
// Block 128x64, BK=32, 4 waves. KV_MODE: cols<256 -> K row-major [4096][256];
// cols>=256 -> V transposed vt[(b*8+head)*32+d][1024 kv].
template <bool BF16_OUT, bool HAS_BIAS, bool KV_MODE>
__global__ __launch_bounds__(256) void mfma_gemm(
    const unsigned short* __restrict__ A, const float* __restrict__ W,
    const float* __restrict__ bias, void* __restrict__ Cv,
    void* __restrict__ Vtp, int M, int N, int K, float oscale) {
  __shared__ unsigned short Asb[128 * 40];
  __shared__ unsigned short Bsb[64 * 40];
  const int tid = threadIdx.x;
  const int w = tid >> 6, l = tid & 63, c = l & 15, g = l >> 4;
  const int wr = w >> 1, wc = w & 1;
  const int m0 = blockIdx.y * 128, n0 = blockIdx.x * 64;
  const int ar = tid >> 1, ah = tid & 1;
  const int bn = tid >> 2, bq = tid & 3;

  f32x4 acc[4][2];
#pragma unroll
  for (int mt = 0; mt < 4; ++mt)
#pragma unroll
    for (int nt = 0; nt < 2; ++nt)
#pragma unroll
      for (int r = 0; r < 4; ++r) acc[mt][nt][r] = 0.f;

  for (int k0 = 0; k0 < K; k0 += 32) {
    __syncthreads();
    {
      const unsigned short* asrc = A + (size_t)(m0 + ar) * K + k0 + ah * 16;
      u16x8 a0 = *reinterpret_cast<const u16x8*>(asrc);
      u16x8 a1 = *reinterpret_cast<const u16x8*>(asrc + 8);
      *reinterpret_cast<u16x8*>(&Asb[ar * 40 + ah * 16]) = a0;
      *reinterpret_cast<u16x8*>(&Asb[ar * 40 + ah * 16 + 8]) = a1;
    }
    {
      const float* wsrc = W + (size_t)(n0 + bn) * K + k0 + bq * 8;
      float4 w0 = *reinterpret_cast<const float4*>(wsrc);
      float4 w1 = *reinterpret_cast<const float4*>(wsrc + 4);
      u16x8 wb;
      wb[0] = f2bf(w0.x); wb[1] = f2bf(w0.y); wb[2] = f2bf(w0.z); wb[3] = f2bf(w0.w);
      wb[4] = f2bf(w1.x); wb[5] = f2bf(w1.y); wb[6] = f2bf(w1.z); wb[7] = f2bf(w1.w);
      *reinterpret_cast<u16x8*>(&Bsb[bn * 40 + bq * 8]) = wb;
    }
    __syncthreads();
    bf16x8 af[4], bfr[2];
#pragma unroll
    for (int mt = 0; mt < 4; ++mt)
      af[mt] = *reinterpret_cast<const bf16x8*>(
          &Asb[(wr * 64 + mt * 16 + c) * 40 + g * 8]);
#pragma unroll
    for (int nt = 0; nt < 2; ++nt)
      bfr[nt] = *reinterpret_cast<const bf16x8*>(
          &Bsb[(wc * 32 + nt * 16 + c) * 40 + g * 8]);
#pragma unroll
    for (int mt = 0; mt < 4; ++mt)
#pragma unroll
      for (int nt = 0; nt < 2; ++nt)
        acc[mt][nt] = __builtin_amdgcn_mfma_f32_16x16x32_bf16(
            af[mt], bfr[nt], acc[mt][nt], 0, 0, 0);
  }

#pragma unroll
  for (int mt = 0; mt < 4; ++mt)
#pragma unroll
    for (int nt = 0; nt < 2; ++nt) {
      int row = m0 + wr * 64 + mt * 16 + g * 4;
      int col = n0 + wc * 32 + nt * 16 + c;
      float bv = HAS_BIAS ? bias[col] : 0.f;
#pragma unroll
      for (int r = 0; r < 4; ++r) {
        float v = acc[mt][nt][r] * oscale + bv;
        if (KV_MODE) {
          if (col < 256) {
            ((unsigned short*)Cv)[(size_t)(row + r) * 256 + col] = f2bf(v);
          } else {
            int head = (col - 256) >> 5, d = (col - 256) & 31;
            int rr = row + r;
            ((unsigned short*)Vtp)[
                ((size_t)(((rr >> 10) << 3) + head) * 32 + d) * 1024 +
                (rr & 1023)] = f2bf(v);
          }
        } else if (BF16_OUT) {
          ((unsigned short*)Cv)[(size_t)(row + r) * N + col] = f2bf(v);
        } else {
          ((float*)Cv)[(size_t)(row + r) * N + col] = v;
        }
      }
    }
}

// ---------------------------------------------------------------------------
// Conv(k=2,s=2) as MFMA GEMM with tap-major K (bf16 x input).
__global__ __launch_bounds__(256) void conv_mfma(
    const unsigned short* __restrict__ Xb, const unsigned short* __restrict__ Wp,
    const float* __restrict__ bias, float* __restrict__ C) {
  __shared__ unsigned short Asb[64 * 40];
  __shared__ unsigned short Bsb[64 * 40];
  const int tid = threadIdx.x;
  const int w = tid >> 6, l = tid & 63, c = l & 15, g = l >> 4;
  const int wr = w >> 1, wc = w & 1;
  const int m0 = blockIdx.y * 64, n0 = blockIdx.x * 64;
  const int sr = tid >> 2, sh = tid & 3;

  int base[4];
  {
    int row = m0 + sr;
    int b = row >> 10, o = row & 1023, oh = o >> 5, ow = o & 31;
#pragma unroll
    for (int tap = 0; tap < 4; ++tap) {
      int n = ((oh << 1) + (tap >> 1)) * 64 + (ow << 1) + (tap & 1);
      base[tap] = ((b << 12) + n) << 8;
    }
  }

  f32x4 acc[2][2];
#pragma unroll
  for (int mt = 0; mt < 2; ++mt)
#pragma unroll
    for (int nt = 0; nt < 2; ++nt)
#pragma unroll
      for (int r = 0; r < 4; ++r) acc[mt][nt][r] = 0.f;

  for (int k0 = 0; k0 < 1024; k0 += 32) {
    const int tap = k0 >> 8, ci0 = (k0 & 255) + sh * 8;
    __syncthreads();
    u16x8 av = *reinterpret_cast<const u16x8*>(&Xb[base[tap] + ci0]);
    *reinterpret_cast<u16x8*>(&Asb[sr * 40 + sh * 8]) = av;
    u16x8 wv = *reinterpret_cast<const u16x8*>(
        &Wp[(size_t)(n0 + sr) * 1024 + k0 + sh * 8]);
    *reinterpret_cast<u16x8*>(&Bsb[sr * 40 + sh * 8]) = wv;
    __syncthreads();
    bf16x8 af[2], bfr[2];
#pragma unroll
    for (int mt = 0; mt < 2; ++mt)
      af[mt] = *reinterpret_cast<const bf16x8*>(
          &Asb[(wr * 32 + mt * 16 + c) * 40 + g * 8]);
#pragma unroll
    for (int nt = 0; nt < 2; ++nt)
      bfr[nt] = *reinterpret_cast<const bf16x8*>(
          &Bsb[(wc * 32 + nt * 16 + c) * 40 + g * 8]);
#pragma unroll
    for (int mt = 0; mt < 2; ++mt)
#pragma unroll
      for (int nt = 0; nt < 2; ++nt)
        acc[mt][nt] = __builtin_amdgcn_mfma_f32_16x16x32_bf16(
            af[mt], bfr[nt], acc[mt][nt], 0, 0, 0);
  }

#pragma unroll
  for (int mt = 0; mt < 2; ++mt)
#pragma unroll
    for (int nt = 0; nt < 2; ++nt) {
      int row = m0 + wr * 32 + mt * 16 + g * 4;
      int col = n0 + wc * 32 + nt * 16 + c;
      float bv = bias[col];
#pragma unroll
      for (int r = 0; r < 4; ++r)
        C[(size_t)(row + r) * 256 + col] = acc[mt][nt][r] + bv;
    }
}

// ---------------------------------------------------------------------------
// LayerNorm over C=256; f32 in, bf16 out.
__global__ __launch_bounds__(256) void ln_kernel(
    const float* __restrict__ xr, const float* __restrict__ gam,
    const float* __restrict__ bet, unsigned short* __restrict__ xo) {
  const int row = blockIdx.x;
  const int t = threadIdx.x;
  float v = xr[(size_t)row * 256 + t];
  float s = v, s2 = v * v;
#pragma unroll
  for (int off = 32; off > 0; off >>= 1) {
    s  += __shfl_down(s, off, 64);
    s2 += __shfl_down(s2, off, 64);
  }
  __shared__ float red[8];
  const int wid = t >> 6;
  if ((t & 63) == 0) { red[wid] = s; red[wid + 4] = s2; }
  __syncthreads();
  s  = red[0] + red[1] + red[2] + red[3];
  s2 = red[4] + red[5] + red[6] + red[7];
  float mean = s * (1.f / 256.f);
  float var = s2 * (1.f / 256.f) - mean * mean;
  float rstd = rsqrtf(var + 1e-5f);
  xo[(size_t)row * 256 + t] = f2bf((v - mean) * rstd * gam[t] + bet[t]);
}

// ---------------------------------------------------------------------------
// 32x32x16-MFMA flash attention: 1 wave/block, 32 q rows, full 1024 KV.
// No LDS, no barriers. K from Kb [4096][256]; V^T from Vt
// [(b*8+h)*32+d][1024]. Q pre-scaled by (1/sqrt(d))*log2e; flat softmax.
// blockIdx: low 5 bits = (b*8+head) for per-XCD L2 KV locality.
__global__ __launch_bounds__(64) void attn_mfma(
    const unsigned short* __restrict__ Qb,
    const unsigned short* __restrict__ Kb,
    const unsigned short* __restrict__ Vt,
    unsigned short* __restrict__ O) {
  const int l = threadIdx.x & 63;
  const int q32 = l & 31, hi = l >> 5;
  const int wg = blockIdx.x;
  const int p = wg & 31, qb = wg >> 5;
  const int b = p >> 3, head = p & 7;
  const int hcol = head << 5;
  const int q0 = (b << 12) + (qb << 5);

  // Q B-frags (pre-scaled)
  bf16x8 qf[2];
  {
    const unsigned short* qp = Qb + (size_t)(q0 + q32) * 256 + hcol + hi * 8;
    qf[0] = *reinterpret_cast<const bf16x8*>(qp);
    qf[1] = *reinterpret_cast<const bf16x8*>(qp + 16);
  }

  const unsigned short* kbase0 =
      Kb + ((size_t)(b << 10) + q32) * 256 + hcol + hi * 8;
  const unsigned short* vrow =
      Vt + ((size_t)((b << 3) + head) * 32 + q32) * 1024 + hi * 8;

  f32x16 acc;
#pragma unroll
  for (int r = 0; r < 16; ++r) acc[r] = 0.f;
  float lsum = 0.f;

  for (int t = 0; t < 16; ++t) {
    // ---- QK^T (swapped): S^T[kv][q] = mfma32(K, Q) ----
    const unsigned short* kbase = kbase0 + (size_t)t * 64 * 256;
    f32x16 s[2];
    {
      bf16x8 k00 = *reinterpret_cast<const bf16x8*>(kbase);
      bf16x8 k01 = *reinterpret_cast<const bf16x8*>(kbase + 16);
      bf16x8 k10 = *reinterpret_cast<const bf16x8*>(kbase + 32 * 256);
      bf16x8 k11 = *reinterpret_cast<const bf16x8*>(kbase + 32 * 256 + 16);
      f32x16 z;
#pragma unroll
      for (int r = 0; r < 16; ++r) z[r] = 0.f;
      s[0] = __builtin_amdgcn_mfma_f32_32x32x16_bf16(k00, qf[0], z, 0, 0, 0);
      s[0] = __builtin_amdgcn_mfma_f32_32x32x16_bf16(k01, qf[1], s[0], 0, 0, 0);
      s[1] = __builtin_amdgcn_mfma_f32_32x32x16_bf16(k10, qf[0], z, 0, 0, 0);
      s[1] = __builtin_amdgcn_mfma_f32_32x32x16_bf16(k11, qf[1], s[1], 0, 0, 0);
    }

    // ---- softmax + in-register P redistribution + PV ----
#pragma unroll
    for (int kvb = 0; kvb < 2; ++kvb) {
      float p16[16];
#pragma unroll
      for (int r = 0; r < 16; ++r) {
        p16[r] = __builtin_amdgcn_exp2f(s[kvb][r]);
        lsum += p16[r];
      }
      unsigned A[8];
#pragma unroll
      for (int i = 0; i < 8; ++i) {
        unsigned o;
        asm("v_cvt_pk_bf16_f32 %0, %1, %2"
            : "=v"(o) : "v"(p16[2 * i]), "v"(p16[2 * i + 1]));
        A[i] = o;
      }
      u32x2v r02 = __builtin_amdgcn_permlane32_swap(A[0], A[2], false, false);
      u32x2v r13 = __builtin_amdgcn_permlane32_swap(A[1], A[3], false, false);
      u32x2v r46 = __builtin_amdgcn_permlane32_swap(A[4], A[6], false, false);
      u32x2v r57 = __builtin_amdgcn_permlane32_swap(A[5], A[7], false, false);
      u32x4v pk0 = {r02[0], r13[0], r02[1], r13[1]};
      u32x4v pk1 = {r46[0], r57[0], r46[1], r57[1]};
      bf16x8 pf0 = __builtin_bit_cast(bf16x8, pk0);
      bf16x8 pf1 = __builtin_bit_cast(bf16x8, pk1);
      const unsigned short* vp = vrow + t * 64 + kvb * 32;
      bf16x8 vf0 = *reinterpret_cast<const bf16x8*>(vp);
      bf16x8 vf1 = *reinterpret_cast<const bf16x8*>(vp + 16);
      acc = __builtin_amdgcn_mfma_f32_32x32x16_bf16(vf0, pf0, acc, 0, 0, 0);
      acc = __builtin_amdgcn_mfma_f32_32x32x16_bf16(vf1, pf1, acc, 0, 0, 0);
    }
  }

  // ---- epilogue: O^T[d][q] regs -> O[q][d] bf16 ----
  lsum += __shfl_xor(lsum, 32, 64);
  float inv = 1.f / lsum;
  unsigned short* orow = O + (size_t)(q0 + q32) * 256 + hcol;
#pragma unroll
  for (int rb = 0; rb < 4; ++rb) {
    const int d0 = rb * 8 + hi * 4;
    float a0 = acc[rb * 4 + 0] * inv, a1 = acc[rb * 4 + 1] * inv;
    float a2 = acc[rb * 4 + 2] * inv, a3 = acc[rb * 4 + 3] * inv;
    unsigned w0, w1;
    asm("v_cvt_pk_bf16_f32 %0, %1, %2" : "=v"(w0) : "v"(a0), "v"(a1));
    asm("v_cvt_pk_bf16_f32 %0, %1, %2" : "=v"(w1) : "v"(a2), "v"(a3));
    unsigned long long pk = (unsigned long long)w0 | ((unsigned long long)w1 << 32);
    *reinterpret_cast<unsigned long long*>(orow + d0) = pk;
  }
}

// ---------------------------------------------------------------------------
extern "C" void kernel_launch(void* const* d_in, const int* in_sizes, int n_in,
                              void* d_out, int out_size, void* d_ws,
                              size_t ws_size, hipStream_t stream) {
  const float* x      = (const float*)d_in[0];
  const float* sr_w   = (const float*)d_in[3];
  const float* sr_b   = (const float*)d_in[4];
  const float* ln_g   = (const float*)d_in[5];
  const float* ln_b   = (const float*)d_in[6];
  const float* q_w    = (const float*)d_in[7];
  const float* kv_w   = (const float*)d_in[8];
  const float* proj_w = (const float*)d_in[9];
  const float* proj_b = (const float*)d_in[10];
  float* out = (float*)d_out;

  char* ws = (char*)d_ws;
  unsigned short* x_bf    = (unsigned short*)(ws);               // 8 MB
  unsigned short* q_bf    = (unsigned short*)(ws + 8388608);     // 8 MB
  unsigned short* srw_bf  = (unsigned short*)(ws + 16777216);    // 512 KB
  float*          xred    = (float*)(ws + 17301504);             // 4 MB
  unsigned short* x_ln    = (unsigned short*)(ws + 21495808);    // 2 MB
  unsigned short* k_buf   = (unsigned short*)(ws + 23592960);    // 2 MB
  unsigned short* vt_buf  = (unsigned short*)(ws + 25690112);    // 2 MB
  unsigned short* attn_bf = (unsigned short*)(ws + 27787264);    // 8 MB

  const float qscale = 0.25506975154985854f;  // (1/sqrt(32)) * log2(e)

  // 0. casts / weight permute
  cast_bf16<<<2048, 256, 0, stream>>>(x, x_bf, 524288);
  perm_srw<<<256, 256, 0, stream>>>(sr_w, srw_bf);
  // 1. q = (x @ q_w^T) * qscale (bf16)
  mfma_gemm<true, false, false><<<dim3(4, 128), 256, 0, stream>>>(
      x_bf, q_w, nullptr, q_bf, nullptr, 16384, 256, 256, qscale);
  // 2. conv(k=2,s=2) + bias (f32)
  conv_mfma<<<dim3(4, 64), 256, 0, stream>>>(x_bf, srw_bf, sr_b, xred);
  // 3. LayerNorm (bf16 out)
  ln_kernel<<<4096, 256, 0, stream>>>(xred, ln_g, ln_b, x_ln);
  // 4. kv = x_ln @ kv_w^T -> K row-major + V transposed
  mfma_gemm<true, false, true><<<dim3(8, 32), 256, 0, stream>>>(
      x_ln, kv_w, nullptr, k_buf, vt_buf, 4096, 512, 256, 1.0f);
  // 5. attention (bf16 out), 1 wave/block, no LDS/barriers
  attn_mfma<<<4096, 64, 0, stream>>>(q_bf, k_buf, vt_buf, attn_bf);
  // 6. out = attn_o @ proj_w^T + proj_b (f32)
  mfma_gemm<false, true, false><<<dim3(4, 128), 256, 0, stream>>>(
      attn_bf, proj_w, proj_b, out, nullptr, 16384, 256, 256, 1.0f);
}

// Round 9
// 102.142 us; speedup vs baseline: 1.3520x; 1.2499x over previous
//
#include <hip/hip_runtime.h>
#include <hip/hip_bf16.h>

// SequenceReductionAttention (PVT-style SRA).
// B=4, N=4096 (64x64), C=256, heads=8, d=32, SR=2 -> N'=1024 (32x32).
//
// Round 9: recombination of verified pieces.
//  - attn: R5 schedule (2 waves, V LDS dbuf, 1 barrier/tile) + K from
//    k_buf [4096][256] (R8 addressing) + V^T staged from vt_buf with pure
//    b128 copies (no pack/transpose VALU) + tree-summed lsum.
//  - q-GEMM and conv merged into ONE dispatch (768 blocks) for machine fill.
//  - cast + sr_w permute merged. 6 dispatches total.

typedef __attribute__((ext_vector_type(8))) short bf16x8;
typedef __attribute__((ext_vector_type(8))) unsigned short u16x8;
typedef __attribute__((ext_vector_type(4))) float f32x4;
typedef __attribute__((ext_vector_type(16))) float f32x16;
typedef __attribute__((ext_vector_type(2))) unsigned u32x2v;
typedef __attribute__((ext_vector_type(4))) unsigned u32x4v;

__device__ inline unsigned short f2bf(float f) {
  unsigned u = __float_as_uint(f);
  u += 0x7fffu + ((u >> 16) & 1u);
  return (unsigned short)(u >> 16);
}

// ---------------------------------------------------------------------------
// prep: blocks [0,2048) cast x f32->bf16 (8 elems/thread);
//       blocks [2048,2304) permute sr_w -> tap-major bf16.
__global__ __launch_bounds__(256) void prep_kernel(
    const float* __restrict__ x, unsigned short* __restrict__ x_bf,
    const float* __restrict__ srw, unsigned short* __restrict__ srw_bf) {
  const int bid = blockIdx.x, t = threadIdx.x;
  if (bid < 2048) {
    int i = bid * 256 + t;
    float4 a = reinterpret_cast<const float4*>(x)[i * 2];
    float4 b = reinterpret_cast<const float4*>(x)[i * 2 + 1];
    ushort4 lo, hi;
    lo.x = f2bf(a.x); lo.y = f2bf(a.y); lo.z = f2bf(a.z); lo.w = f2bf(a.w);
    hi.x = f2bf(b.x); hi.y = f2bf(b.y); hi.z = f2bf(b.z); hi.w = f2bf(b.w);
    reinterpret_cast<ushort4*>(x_bf)[i * 2] = lo;
    reinterpret_cast<ushort4*>(x_bf)[i * 2 + 1] = hi;
  } else {
    int o = bid - 2048;
    float4 v = reinterpret_cast<const float4*>(srw + (size_t)o * 1024)[t];
    srw_bf[(size_t)o * 1024 + 0 * 256 + t] = f2bf(v.x);
    srw_bf[(size_t)o * 1024 + 1 * 256 + t] = f2bf(v.y);
    srw_bf[(size_t)o * 1024 + 2 * 256 + t] = f2bf(v.z);
    srw_bf[(size_t)o * 1024 + 3 * 256 + t] = f2bf(v.w);
  }
}

// ---------------------------------------------------------------------------
// GEMM body: C[M,N](bf16) = (A[M,K]bf16 @ W[N,K]f32->bf16 ^T) * oscale.
// 128x64 tile, BK=32, 4 waves. Asb 128*40 u16, Bsb 64*40 u16.
__device__ __forceinline__ void gemm_body_q(
    const unsigned short* __restrict__ A, const float* __restrict__ W,
    unsigned short* __restrict__ C, int K, int N, float oscale,
    int m0, int n0, unsigned short* Asb, unsigned short* Bsb) {
  const int tid = threadIdx.x;
  const int w = tid >> 6, l = tid & 63, c = l & 15, g = l >> 4;
  const int wr = w >> 1, wc = w & 1;
  const int ar = tid >> 1, ah = tid & 1;
  const int bn = tid >> 2, bq = tid & 3;

  f32x4 acc[4][2];
#pragma unroll
  for (int mt = 0; mt < 4; ++mt)
#pragma unroll
    for (int nt = 0; nt < 2; ++nt)
#pragma unroll
      for (int r = 0; r < 4; ++r) acc[mt][nt][r] = 0.f;

  for (int k0 = 0; k0 < K; k0 += 32) {
    __syncthreads();
    {
      const unsigned short* asrc = A + (size_t)(m0 + ar) * K + k0 + ah * 16;
      u16x8 a0 = *reinterpret_cast<const u16x8*>(asrc);
      u16x8 a1 = *reinterpret_cast<const u16x8*>(asrc + 8);
      *reinterpret_cast<u16x8*>(&Asb[ar * 40 + ah * 16]) = a0;
      *reinterpret_cast<u16x8*>(&Asb[ar * 40 + ah * 16 + 8]) = a1;
    }
    {
      const float* wsrc = W + (size_t)(n0 + bn) * K + k0 + bq * 8;
      float4 w0 = *reinterpret_cast<const float4*>(wsrc);
      float4 w1 = *reinterpret_cast<const float4*>(wsrc + 4);
      u16x8 wb;
      wb[0] = f2bf(w0.x); wb[1] = f2bf(w0.y); wb[2] = f2bf(w0.z); wb[3] = f2bf(w0.w);
      wb[4] = f2bf(w1.x); wb[5] = f2bf(w1.y); wb[6] = f2bf(w1.z); wb[7] = f2bf(w1.w);
      *reinterpret_cast<u16x8*>(&Bsb[bn * 40 + bq * 8]) = wb;
    }
    __syncthreads();
    bf16x8 af[4], bfr[2];
#pragma unroll
    for (int mt = 0; mt < 4; ++mt)
      af[mt] = *reinterpret_cast<const bf16x8*>(
          &Asb[(wr * 64 + mt * 16 + c) * 40 + g * 8]);
#pragma unroll
    for (int nt = 0; nt < 2; ++nt)
      bfr[nt] = *reinterpret_cast<const bf16x8*>(
          &Bsb[(wc * 32 + nt * 16 + c) * 40 + g * 8]);
#pragma unroll
    for (int mt = 0; mt < 4; ++mt)
#pragma unroll
      for (int nt = 0; nt < 2; ++nt)
        acc[mt][nt] = __builtin_amdgcn_mfma_f32_16x16x32_bf16(
            af[mt], bfr[nt], acc[mt][nt], 0, 0, 0);
  }

#pragma unroll
  for (int mt = 0; mt < 4; ++mt)
#pragma unroll
    for (int nt = 0; nt < 2; ++nt) {
      int row = m0 + wr * 64 + mt * 16 + g * 4;
      int col = n0 + wc * 32 + nt * 16 + c;
#pragma unroll
      for (int r = 0; r < 4; ++r)
        C[(size_t)(row + r) * N + col] = f2bf(acc[mt][nt][r] * oscale);
    }
}

// ---------------------------------------------------------------------------
// Conv body: 64x64 tile, tap-major K=1024, bf16 x. As/Bs 64*40 u16 each.
__device__ __forceinline__ void conv_body(
    const unsigned short* __restrict__ Xb, const unsigned short* __restrict__ Wp,
    const float* __restrict__ bias, float* __restrict__ C,
    int m0, int n0, unsigned short* Asb, unsigned short* Bsb) {
  const int tid = threadIdx.x;
  const int w = tid >> 6, l = tid & 63, c = l & 15, g = l >> 4;
  const int wr = w >> 1, wc = w & 1;
  const int sr = tid >> 2, sh = tid & 3;

  int base[4];
  {
    int row = m0 + sr;
    int b = row >> 10, o = row & 1023, oh = o >> 5, ow = o & 31;
#pragma unroll
    for (int tap = 0; tap < 4; ++tap) {
      int n = ((oh << 1) + (tap >> 1)) * 64 + (ow << 1) + (tap & 1);
      base[tap] = ((b << 12) + n) << 8;
    }
  }

  f32x4 acc[2][2];
#pragma unroll
  for (int mt = 0; mt < 2; ++mt)
#pragma unroll
    for (int nt = 0; nt < 2; ++nt)
#pragma unroll
      for (int r = 0; r < 4; ++r) acc[mt][nt][r] = 0.f;

  for (int k0 = 0; k0 < 1024; k0 += 32) {
    const int tap = k0 >> 8, ci0 = (k0 & 255) + sh * 8;
    __syncthreads();
    u16x8 av = *reinterpret_cast<const u16x8*>(&Xb[base[tap] + ci0]);
    *reinterpret_cast<u16x8*>(&Asb[sr * 40 + sh * 8]) = av;
    u16x8 wv = *reinterpret_cast<const u16x8*>(
        &Wp[(size_t)(n0 + sr) * 1024 + k0 + sh * 8]);
    *reinterpret_cast<u16x8*>(&Bsb[sr * 40 + sh * 8]) = wv;
    __syncthreads();
    bf16x8 af[2], bfr[2];
#pragma unroll
    for (int mt = 0; mt < 2; ++mt)
      af[mt] = *reinterpret_cast<const bf16x8*>(
          &Asb[(wr * 32 + mt * 16 + c) * 40 + g * 8]);
#pragma unroll
    for (int nt = 0; nt < 2; ++nt)
      bfr[nt] = *reinterpret_cast<const bf16x8*>(
          &Bsb[(wc * 32 + nt * 16 + c) * 40 + g * 8]);
#pragma unroll
    for (int mt = 0; mt < 2; ++mt)
#pragma unroll
      for (int nt = 0; nt < 2; ++nt)
        acc[mt][nt] = __builtin_amdgcn_mfma_f32_16x16x32_bf16(
            af[mt], bfr[nt], acc[mt][nt], 0, 0, 0);
  }

#pragma unroll
  for (int mt = 0; mt < 2; ++mt)
#pragma unroll
    for (int nt = 0; nt < 2; ++nt) {
      int row = m0 + wr * 32 + mt * 16 + g * 4;
      int col = n0 + wc * 32 + nt * 16 + c;
      float bv = bias[col];
#pragma unroll
      for (int r = 0; r < 4; ++r)
        C[(size_t)(row + r) * 256 + col] = acc[mt][nt][r] + bv;
    }
}

// ---------------------------------------------------------------------------
// Fused dispatch: blocks [0,512) = q GEMM (x_bf @ q_w^T * qscale -> q_bf),
// blocks [512,768) = conv (x_bf (*) srw_bf + sr_b -> xred).
__global__ __launch_bounds__(256) void qconv_kernel(
    const unsigned short* __restrict__ x_bf, const float* __restrict__ q_w,
    unsigned short* __restrict__ q_bf, const unsigned short* __restrict__ srw_bf,
    const float* __restrict__ sr_b, float* __restrict__ xred, float qscale) {
  __shared__ unsigned short smem[128 * 40 + 64 * 40];
  const int bid = blockIdx.x;
  if (bid < 512) {
    gemm_body_q(x_bf, q_w, q_bf, 256, 256, qscale,
                (bid >> 2) * 128, (bid & 3) * 64, smem, smem + 128 * 40);
  } else {
    int cb = bid - 512;
    conv_body(x_bf, srw_bf, sr_b, xred,
              (cb >> 2) * 64, (cb & 3) * 64, smem, smem + 64 * 40);
  }
}

// ---------------------------------------------------------------------------
// MFMA GEMM (standalone): used for kv (KV_MODE: K row-major + V^T) and proj.
template <bool BF16_OUT, bool HAS_BIAS, bool KV_MODE>
__global__ __launch_bounds__(256) void mfma_gemm(
    const unsigned short* __restrict__ A, const float* __restrict__ W,
    const float* __restrict__ bias, void* __restrict__ Cv,
    void* __restrict__ Vtp, int M, int N, int K, float oscale) {
  __shared__ unsigned short Asb[128 * 40];
  __shared__ unsigned short Bsb[64 * 40];
  const int tid = threadIdx.x;
  const int w = tid >> 6, l = tid & 63, c = l & 15, g = l >> 4;
  const int wr = w >> 1, wc = w & 1;
  const int m0 = blockIdx.y * 128, n0 = blockIdx.x * 64;
  const int ar = tid >> 1, ah = tid & 1;
  const int bn = tid >> 2, bq = tid & 3;

  f32x4 acc[4][2];
#pragma unroll
  for (int mt = 0; mt < 4; ++mt)
#pragma unroll
    for (int nt = 0; nt < 2; ++nt)
#pragma unroll
      for (int r = 0; r < 4; ++r) acc[mt][nt][r] = 0.f;

  for (int k0 = 0; k0 < K; k0 += 32) {
    __syncthreads();
    {
      const unsigned short* asrc = A + (size_t)(m0 + ar) * K + k0 + ah * 16;
      u16x8 a0 = *reinterpret_cast<const u16x8*>(asrc);
      u16x8 a1 = *reinterpret_cast<const u16x8*>(asrc + 8);
      *reinterpret_cast<u16x8*>(&Asb[ar * 40 + ah * 16]) = a0;
      *reinterpret_cast<u16x8*>(&Asb[ar * 40 + ah * 16 + 8]) = a1;
    }
    {
      const float* wsrc = W + (size_t)(n0 + bn) * K + k0 + bq * 8;
      float4 w0 = *reinterpret_cast<const float4*>(wsrc);
      float4 w1 = *reinterpret_cast<const float4*>(wsrc + 4);
      u16x8 wb;
      wb[0] = f2bf(w0.x); wb[1] = f2bf(w0.y); wb[2] = f2bf(w0.z); wb[3] = f2bf(w0.w);
      wb[4] = f2bf(w1.x); wb[5] = f2bf(w1.y); wb[6] = f2bf(w1.z); wb[7] = f2bf(w1.w);
      *reinterpret_cast<u16x8*>(&Bsb[bn * 40 + bq * 8]) = wb;
    }
    __syncthreads();
    bf16x8 af[4], bfr[2];
#pragma unroll
    for (int mt = 0; mt < 4; ++mt)
      af[mt] = *reinterpret_cast<const bf16x8*>(
          &Asb[(wr * 64 + mt * 16 + c) * 40 + g * 8]);
#pragma unroll
    for (int nt = 0; nt < 2; ++nt)
      bfr[nt] = *reinterpret_cast<const bf16x8*>(
          &Bsb[(wc * 32 + nt * 16 + c) * 40 + g * 8]);
#pragma unroll
    for (int mt = 0; mt < 4; ++mt)
#pragma unroll
      for (int nt = 0; nt < 2; ++nt)
        acc[mt][nt] = __builtin_amdgcn_mfma_f32_16x16x32_bf16(
            af[mt], bfr[nt], acc[mt][nt], 0, 0, 0);
  }

#pragma unroll
  for (int mt = 0; mt < 4; ++mt)
#pragma unroll
    for (int nt = 0; nt < 2; ++nt) {
      int row = m0 + wr * 64 + mt * 16 + g * 4;
      int col = n0 + wc * 32 + nt * 16 + c;
      float bv = HAS_BIAS ? bias[col] : 0.f;
#pragma unroll
      for (int r = 0; r < 4; ++r) {
        float v = acc[mt][nt][r] * oscale + bv;
        if (KV_MODE) {
          if (col < 256) {
            ((unsigned short*)Cv)[(size_t)(row + r) * 256 + col] = f2bf(v);
          } else {
            int head = (col - 256) >> 5, d = (col - 256) & 31;
            int rr = row + r;
            ((unsigned short*)Vtp)[
                ((size_t)(((rr >> 10) << 3) + head) * 32 + d) * 1024 +
                (rr & 1023)] = f2bf(v);
          }
        } else if (BF16_OUT) {
          ((unsigned short*)Cv)[(size_t)(row + r) * N + col] = f2bf(v);
        } else {
          ((float*)Cv)[(size_t)(row + r) * N + col] = v;
        }
      }
    }
}

// ---------------------------------------------------------------------------
// LayerNorm over C=256; f32 in, bf16 out.
__global__ __launch_bounds__(256) void ln_kernel(
    const float* __restrict__ xr, const float* __restrict__ gam,
    const float* __restrict__ bet, unsigned short* __restrict__ xo) {
  const int row = blockIdx.x;
  const int t = threadIdx.x;
  float v = xr[(size_t)row * 256 + t];
  float s = v, s2 = v * v;
#pragma unroll
  for (int off = 32; off > 0; off >>= 1) {
    s  += __shfl_down(s, off, 64);
    s2 += __shfl_down(s2, off, 64);
  }
  __shared__ float red[8];
  const int wid = t >> 6;
  if ((t & 63) == 0) { red[wid] = s; red[wid + 4] = s2; }
  __syncthreads();
  s  = red[0] + red[1] + red[2] + red[3];
  s2 = red[4] + red[5] + red[6] + red[7];
  float mean = s * (1.f / 256.f);
  float var = s2 * (1.f / 256.f) - mean * mean;
  float rstd = rsqrtf(var + 1e-5f);
  xo[(size_t)row * 256 + t] = f2bf((v - mean) * rstd * gam[t] + bet[t]);
}

// ---------------------------------------------------------------------------
// 32x32x16-MFMA flash attention. R5 schedule: 2 waves/block (64 q rows),
// V^T LDS double-buffer, 1 barrier/tile, reg-prefetch of next V tile.
// K from Kb [4096][256]; V^T staged from Vtg [(b*8+h)*32+d][1024] with
// pure b128 copies (no transpose VALU). Q pre-scaled; flat softmax,
// tree-summed lsum.
__global__ __launch_bounds__(128) void attn_mfma(
    const unsigned short* __restrict__ Qb,
    const unsigned short* __restrict__ Kb,
    const unsigned short* __restrict__ Vtg,
    unsigned short* __restrict__ O) {
  __shared__ __align__(16) unsigned short Vt[2][32][72];

  const int tid = threadIdx.x;
  const int l = tid & 63;
  const int w = tid >> 6;
  const int q32 = l & 31, hi = l >> 5;
  const int wg = blockIdx.x;
  const int qb = wg & 63, head = (wg >> 6) & 7, b = wg >> 9;
  const int hcol = head << 5;
  const int q0 = (b << 12) + (qb << 6) + (w << 5);

  // Q B-frags (pre-scaled)
  bf16x8 qf[2];
  {
    const unsigned short* qp = Qb + (size_t)(q0 + q32) * 256 + hcol + hi * 8;
    qf[0] = *reinterpret_cast<const bf16x8*>(qp);
    qf[1] = *reinterpret_cast<const bf16x8*>(qp + 16);
  }

  // V staging: thread -> (d = tid>>2, kv chunk = (tid&3)*16), 16 elems b128x2.
  const int sd = tid >> 2, skv = (tid & 3) << 4;
  const unsigned short* vtrow =
      Vtg + ((size_t)((b << 3) + head) * 32 + sd) * 1024 + skv;

  // prologue: stage V^T tile 0 into buf 0
  {
    u16x8 a = *reinterpret_cast<const u16x8*>(vtrow);
    u16x8 bv = *reinterpret_cast<const u16x8*>(vtrow + 8);
    *reinterpret_cast<u16x8*>(&Vt[0][sd][skv]) = a;
    *reinterpret_cast<u16x8*>(&Vt[0][sd][skv + 8]) = bv;
  }

  const unsigned short* kbase0 =
      Kb + ((size_t)(b << 10) + q32) * 256 + hcol + hi * 8;

  f32x16 acc;
#pragma unroll
  for (int r = 0; r < 16; ++r) acc[r] = 0.f;
  float lsum = 0.f;

  for (int t = 0; t < 16; ++t) {
    const int cur = t & 1;
    __syncthreads();

    // prefetch next V tile into regs (hides under QK+softmax)
    u16x8 nv0, nv1;
    if (t < 15) {
      const unsigned short* vp = vtrow + (t + 1) * 64;
      nv0 = *reinterpret_cast<const u16x8*>(vp);
      nv1 = *reinterpret_cast<const u16x8*>(vp + 8);
    }

    // ---- QK^T (swapped): S^T[kv][q] = mfma32(K, Q) ----
    const unsigned short* kbase = kbase0 + (size_t)t * 64 * 256;
    f32x16 s[2];
    {
      bf16x8 k00 = *reinterpret_cast<const bf16x8*>(kbase);
      bf16x8 k01 = *reinterpret_cast<const bf16x8*>(kbase + 16);
      bf16x8 k10 = *reinterpret_cast<const bf16x8*>(kbase + 32 * 256);
      bf16x8 k11 = *reinterpret_cast<const bf16x8*>(kbase + 32 * 256 + 16);
      f32x16 z;
#pragma unroll
      for (int r = 0; r < 16; ++r) z[r] = 0.f;
      s[0] = __builtin_amdgcn_mfma_f32_32x32x16_bf16(k00, qf[0], z, 0, 0, 0);
      s[0] = __builtin_amdgcn_mfma_f32_32x32x16_bf16(k01, qf[1], s[0], 0, 0, 0);
      s[1] = __builtin_amdgcn_mfma_f32_32x32x16_bf16(k10, qf[0], z, 0, 0, 0);
      s[1] = __builtin_amdgcn_mfma_f32_32x32x16_bf16(k11, qf[1], s[1], 0, 0, 0);
    }

    // ---- softmax + in-register P redistribution + PV ----
#pragma unroll
    for (int kvb = 0; kvb < 2; ++kvb) {
      float p16[16];
#pragma unroll
      for (int r = 0; r < 16; ++r)
        p16[r] = __builtin_amdgcn_exp2f(s[kvb][r]);
      float s0 = (p16[0] + p16[1]) + (p16[2] + p16[3]);
      float s1 = (p16[4] + p16[5]) + (p16[6] + p16[7]);
      float s2 = (p16[8] + p16[9]) + (p16[10] + p16[11]);
      float s3 = (p16[12] + p16[13]) + (p16[14] + p16[15]);
      lsum += (s0 + s1) + (s2 + s3);
      unsigned A[8];
#pragma unroll
      for (int i = 0; i < 8; ++i) {
        unsigned o;
        asm("v_cvt_pk_bf16_f32 %0, %1, %2"
            : "=v"(o) : "v"(p16[2 * i]), "v"(p16[2 * i + 1]));
        A[i] = o;
      }
      u32x2v r02 = __builtin_amdgcn_permlane32_swap(A[0], A[2], false, false);
      u32x2v r13 = __builtin_amdgcn_permlane32_swap(A[1], A[3], false, false);
      u32x2v r46 = __builtin_amdgcn_permlane32_swap(A[4], A[6], false, false);
      u32x2v r57 = __builtin_amdgcn_permlane32_swap(A[5], A[7], false, false);
      u32x4v pk0 = {r02[0], r13[0], r02[1], r13[1]};
      u32x4v pk1 = {r46[0], r57[0], r46[1], r57[1]};
      bf16x8 pf0 = __builtin_bit_cast(bf16x8, pk0);
      bf16x8 pf1 = __builtin_bit_cast(bf16x8, pk1);
      const unsigned short* vrow = &Vt[cur][q32][kvb * 32 + hi * 8];
      bf16x8 vf0 = *reinterpret_cast<const bf16x8*>(vrow);
      bf16x8 vf1 = *reinterpret_cast<const bf16x8*>(vrow + 16);
      acc = __builtin_amdgcn_mfma_f32_32x32x16_bf16(vf0, pf0, acc, 0, 0, 0);
      acc = __builtin_amdgcn_mfma_f32_32x32x16_bf16(vf1, pf1, acc, 0, 0, 0);
    }

    // ---- write prefetched V into the other buffer ----
    if (t < 15) {
      *reinterpret_cast<u16x8*>(&Vt[cur ^ 1][sd][skv]) = nv0;
      *reinterpret_cast<u16x8*>(&Vt[cur ^ 1][sd][skv + 8]) = nv1;
    }
  }

  // ---- epilogue: O^T[d][q] regs -> O[q][d] bf16 ----
  lsum += __shfl_xor(lsum, 32, 64);
  float inv = 1.f / lsum;
  unsigned short* orow = O + (size_t)(q0 + q32) * 256 + hcol;
#pragma unroll
  for (int rb = 0; rb < 4; ++rb) {
    const int d0 = rb * 8 + hi * 4;
    float a0 = acc[rb * 4 + 0] * inv, a1 = acc[rb * 4 + 1] * inv;
    float a2 = acc[rb * 4 + 2] * inv, a3 = acc[rb * 4 + 3] * inv;
    unsigned w0, w1;
    asm("v_cvt_pk_bf16_f32 %0, %1, %2" : "=v"(w0) : "v"(a0), "v"(a1));
    asm("v_cvt_pk_bf16_f32 %0, %1, %2" : "=v"(w1) : "v"(a2), "v"(a3));
    unsigned long long pk = (unsigned long long)w0 | ((unsigned long long)w1 << 32);
    *reinterpret_cast<unsigned long long*>(orow + d0) = pk;
  }
}

// ---------------------------------------------------------------------------
extern "C" void kernel_launch(void* const* d_in, const int* in_sizes, int n_in,
                              void* d_out, int out_size, void* d_ws,
                              size_t ws_size, hipStream_t stream) {
  const float* x      = (const float*)d_in[0];
  const float* sr_w   = (const float*)d_in[3];
  const float* sr_b   = (const float*)d_in[4];
  const float* ln_g   = (const float*)d_in[5];
  const float* ln_b   = (const float*)d_in[6];
  const float* q_w    = (const float*)d_in[7];
  const float* kv_w   = (const float*)d_in[8];
  const float* proj_w = (const float*)d_in[9];
  const float* proj_b = (const float*)d_in[10];
  float* out = (float*)d_out;

  char* ws = (char*)d_ws;
  unsigned short* x_bf    = (unsigned short*)(ws);               // 8 MB
  unsigned short* q_bf    = (unsigned short*)(ws + 8388608);     // 8 MB
  unsigned short* srw_bf  = (unsigned short*)(ws + 16777216);    // 512 KB
  float*          xred    = (float*)(ws + 17301504);             // 4 MB
  unsigned short* x_ln    = (unsigned short*)(ws + 21495808);    // 2 MB
  unsigned short* k_buf   = (unsigned short*)(ws + 23592960);    // 2 MB
  unsigned short* vt_buf  = (unsigned short*)(ws + 25690112);    // 2 MB
  unsigned short* attn_bf = (unsigned short*)(ws + 27787264);    // 8 MB

  const float qscale = 0.25506975154985854f;  // (1/sqrt(32)) * log2(e)

  // 1. prep: x cast + sr_w permute
  prep_kernel<<<2304, 256, 0, stream>>>(x, x_bf, sr_w, srw_bf);
  // 2. fused q GEMM (512 blocks) + conv (256 blocks)
  qconv_kernel<<<768, 256, 0, stream>>>(
      x_bf, q_w, q_bf, srw_bf, sr_b, xred, qscale);
  // 3. LayerNorm (bf16 out)
  ln_kernel<<<4096, 256, 0, stream>>>(xred, ln_g, ln_b, x_ln);
  // 4. kv = x_ln @ kv_w^T -> K row-major + V transposed
  mfma_gemm<true, false, true><<<dim3(8, 32), 256, 0, stream>>>(
      x_ln, kv_w, nullptr, k_buf, vt_buf, 4096, 512, 256, 1.0f);
  // 5. attention (bf16 out)
  attn_mfma<<<2048, 128, 0, stream>>>(q_bf, k_buf, vt_buf, attn_bf);
  // 6. out = attn_o @ proj_w^T + proj_b (f32)
  mfma_gemm<false, true, false><<<dim3(4, 128), 256, 0, stream>>>(
      attn_bf, proj_w, proj_b, out, nullptr, 16384, 256, 256, 1.0f);
}

// Round 10
// 96.357 us; speedup vs baseline: 1.4331x; 1.0600x over previous
//
#include <hip/hip_runtime.h>
#include <hip/hip_bf16.h>

// SequenceReductionAttention (PVT-style SRA).
// B=4, N=4096 (64x64), C=256, heads=8, d=32, SR=2 -> N'=1024 (32x32).
//
// Round 10:
//  - attn: K now LDS double-buffered like V (reg-prefetch 1 tile ahead,
//    pure b128 copies, [64][36] pad = phase-conflict-free). K global
//    latency leaves the per-tile dependent chain.
//  - x f32->bf16 cast pass deleted: q GEMM + conv stage from f32 x with
//    f2bf in the stager. prep = sr_w permute only (256 blocks).
//  - LN: one wave per row, float4 loads, no LDS/barrier.

typedef __attribute__((ext_vector_type(8))) short bf16x8;
typedef __attribute__((ext_vector_type(8))) unsigned short u16x8;
typedef __attribute__((ext_vector_type(4))) float f32x4;
typedef __attribute__((ext_vector_type(16))) float f32x16;
typedef __attribute__((ext_vector_type(2))) unsigned u32x2v;
typedef __attribute__((ext_vector_type(4))) unsigned u32x4v;

__device__ inline unsigned short f2bf(float f) {
  unsigned u = __float_as_uint(f);
  u += 0x7fffu + ((u >> 16) & 1u);
  return (unsigned short)(u >> 16);
}

// ---------------------------------------------------------------------------
// prep: permute sr_w [256 o][256 ci][4 tap] f32 -> [256 o][4 tap][256 ci] bf16.
__global__ __launch_bounds__(256) void prep_kernel(
    const float* __restrict__ srw, unsigned short* __restrict__ srw_bf) {
  const int o = blockIdx.x, t = threadIdx.x;
  float4 v = reinterpret_cast<const float4*>(srw + (size_t)o * 1024)[t];
  srw_bf[(size_t)o * 1024 + 0 * 256 + t] = f2bf(v.x);
  srw_bf[(size_t)o * 1024 + 1 * 256 + t] = f2bf(v.y);
  srw_bf[(size_t)o * 1024 + 2 * 256 + t] = f2bf(v.z);
  srw_bf[(size_t)o * 1024 + 3 * 256 + t] = f2bf(v.w);
}

// ---------------------------------------------------------------------------
// GEMM body: C[M,N](bf16) = (A[M,K]f32->bf16 @ W[N,K]f32->bf16 ^T) * oscale.
// 128x64 tile, BK=32, 4 waves.
__device__ __forceinline__ void gemm_body_q(
    const float* __restrict__ Af, const float* __restrict__ W,
    unsigned short* __restrict__ C, int K, int N, float oscale,
    int m0, int n0, unsigned short* Asb, unsigned short* Bsb) {
  const int tid = threadIdx.x;
  const int w = tid >> 6, l = tid & 63, c = l & 15, g = l >> 4;
  const int wr = w >> 1, wc = w & 1;
  const int ar = tid >> 1, ah = tid & 1;
  const int bn = tid >> 2, bq = tid & 3;

  f32x4 acc[4][2];
#pragma unroll
  for (int mt = 0; mt < 4; ++mt)
#pragma unroll
    for (int nt = 0; nt < 2; ++nt)
#pragma unroll
      for (int r = 0; r < 4; ++r) acc[mt][nt][r] = 0.f;

  for (int k0 = 0; k0 < K; k0 += 32) {
    __syncthreads();
    {
      const float* asrc = Af + (size_t)(m0 + ar) * K + k0 + ah * 16;
      float4 a0 = *reinterpret_cast<const float4*>(asrc);
      float4 a1 = *reinterpret_cast<const float4*>(asrc + 4);
      float4 a2 = *reinterpret_cast<const float4*>(asrc + 8);
      float4 a3 = *reinterpret_cast<const float4*>(asrc + 12);
      u16x8 w0, w1;
      w0[0] = f2bf(a0.x); w0[1] = f2bf(a0.y); w0[2] = f2bf(a0.z); w0[3] = f2bf(a0.w);
      w0[4] = f2bf(a1.x); w0[5] = f2bf(a1.y); w0[6] = f2bf(a1.z); w0[7] = f2bf(a1.w);
      w1[0] = f2bf(a2.x); w1[1] = f2bf(a2.y); w1[2] = f2bf(a2.z); w1[3] = f2bf(a2.w);
      w1[4] = f2bf(a3.x); w1[5] = f2bf(a3.y); w1[6] = f2bf(a3.z); w1[7] = f2bf(a3.w);
      *reinterpret_cast<u16x8*>(&Asb[ar * 40 + ah * 16]) = w0;
      *reinterpret_cast<u16x8*>(&Asb[ar * 40 + ah * 16 + 8]) = w1;
    }
    {
      const float* wsrc = W + (size_t)(n0 + bn) * K + k0 + bq * 8;
      float4 w0 = *reinterpret_cast<const float4*>(wsrc);
      float4 w1 = *reinterpret_cast<const float4*>(wsrc + 4);
      u16x8 wb;
      wb[0] = f2bf(w0.x); wb[1] = f2bf(w0.y); wb[2] = f2bf(w0.z); wb[3] = f2bf(w0.w);
      wb[4] = f2bf(w1.x); wb[5] = f2bf(w1.y); wb[6] = f2bf(w1.z); wb[7] = f2bf(w1.w);
      *reinterpret_cast<u16x8*>(&Bsb[bn * 40 + bq * 8]) = wb;
    }
    __syncthreads();
    bf16x8 af[4], bfr[2];
#pragma unroll
    for (int mt = 0; mt < 4; ++mt)
      af[mt] = *reinterpret_cast<const bf16x8*>(
          &Asb[(wr * 64 + mt * 16 + c) * 40 + g * 8]);
#pragma unroll
    for (int nt = 0; nt < 2; ++nt)
      bfr[nt] = *reinterpret_cast<const bf16x8*>(
          &Bsb[(wc * 32 + nt * 16 + c) * 40 + g * 8]);
#pragma unroll
    for (int mt = 0; mt < 4; ++mt)
#pragma unroll
      for (int nt = 0; nt < 2; ++nt)
        acc[mt][nt] = __builtin_amdgcn_mfma_f32_16x16x32_bf16(
            af[mt], bfr[nt], acc[mt][nt], 0, 0, 0);
  }

#pragma unroll
  for (int mt = 0; mt < 4; ++mt)
#pragma unroll
    for (int nt = 0; nt < 2; ++nt) {
      int row = m0 + wr * 64 + mt * 16 + g * 4;
      int col = n0 + wc * 32 + nt * 16 + c;
#pragma unroll
      for (int r = 0; r < 4; ++r)
        C[(size_t)(row + r) * N + col] = f2bf(acc[mt][nt][r] * oscale);
    }
}

// ---------------------------------------------------------------------------
// Conv body: 64x64 tile, tap-major K=1024, f32 x cast on stage.
__device__ __forceinline__ void conv_body(
    const float* __restrict__ Xf, const unsigned short* __restrict__ Wp,
    const float* __restrict__ bias, float* __restrict__ C,
    int m0, int n0, unsigned short* Asb, unsigned short* Bsb) {
  const int tid = threadIdx.x;
  const int w = tid >> 6, l = tid & 63, c = l & 15, g = l >> 4;
  const int wr = w >> 1, wc = w & 1;
  const int sr = tid >> 2, sh = tid & 3;

  int base[4];
  {
    int row = m0 + sr;
    int b = row >> 10, o = row & 1023, oh = o >> 5, ow = o & 31;
#pragma unroll
    for (int tap = 0; tap < 4; ++tap) {
      int n = ((oh << 1) + (tap >> 1)) * 64 + (ow << 1) + (tap & 1);
      base[tap] = ((b << 12) + n) << 8;
    }
  }

  f32x4 acc[2][2];
#pragma unroll
  for (int mt = 0; mt < 2; ++mt)
#pragma unroll
    for (int nt = 0; nt < 2; ++nt)
#pragma unroll
      for (int r = 0; r < 4; ++r) acc[mt][nt][r] = 0.f;

  for (int k0 = 0; k0 < 1024; k0 += 32) {
    const int tap = k0 >> 8, ci0 = (k0 & 255) + sh * 8;
    __syncthreads();
    {
      const float* xp = Xf + base[tap] + ci0;
      float4 a0 = *reinterpret_cast<const float4*>(xp);
      float4 a1 = *reinterpret_cast<const float4*>(xp + 4);
      u16x8 av;
      av[0] = f2bf(a0.x); av[1] = f2bf(a0.y); av[2] = f2bf(a0.z); av[3] = f2bf(a0.w);
      av[4] = f2bf(a1.x); av[5] = f2bf(a1.y); av[6] = f2bf(a1.z); av[7] = f2bf(a1.w);
      *reinterpret_cast<u16x8*>(&Asb[sr * 40 + sh * 8]) = av;
    }
    u16x8 wv = *reinterpret_cast<const u16x8*>(
        &Wp[(size_t)(n0 + sr) * 1024 + k0 + sh * 8]);
    *reinterpret_cast<u16x8*>(&Bsb[sr * 40 + sh * 8]) = wv;
    __syncthreads();
    bf16x8 af[2], bfr[2];
#pragma unroll
    for (int mt = 0; mt < 2; ++mt)
      af[mt] = *reinterpret_cast<const bf16x8*>(
          &Asb[(wr * 32 + mt * 16 + c) * 40 + g * 8]);
#pragma unroll
    for (int nt = 0; nt < 2; ++nt)
      bfr[nt] = *reinterpret_cast<const bf16x8*>(
          &Bsb[(wc * 32 + nt * 16 + c) * 40 + g * 8]);
#pragma unroll
    for (int mt = 0; mt < 2; ++mt)
#pragma unroll
      for (int nt = 0; nt < 2; ++nt)
        acc[mt][nt] = __builtin_amdgcn_mfma_f32_16x16x32_bf16(
            af[mt], bfr[nt], acc[mt][nt], 0, 0, 0);
  }

#pragma unroll
  for (int mt = 0; mt < 2; ++mt)
#pragma unroll
    for (int nt = 0; nt < 2; ++nt) {
      int row = m0 + wr * 32 + mt * 16 + g * 4;
      int col = n0 + wc * 32 + nt * 16 + c;
      float bv = bias[col];
#pragma unroll
      for (int r = 0; r < 4; ++r)
        C[(size_t)(row + r) * 256 + col] = acc[mt][nt][r] + bv;
    }
}

// ---------------------------------------------------------------------------
// Fused dispatch: blocks [0,512) = q GEMM, blocks [512,768) = conv.
__global__ __launch_bounds__(256) void qconv_kernel(
    const float* __restrict__ x, const float* __restrict__ q_w,
    unsigned short* __restrict__ q_bf, const unsigned short* __restrict__ srw_bf,
    const float* __restrict__ sr_b, float* __restrict__ xred, float qscale) {
  __shared__ unsigned short smem[128 * 40 + 64 * 40];
  const int bid = blockIdx.x;
  if (bid < 512) {
    gemm_body_q(x, q_w, q_bf, 256, 256, qscale,
                (bid >> 2) * 128, (bid & 3) * 64, smem, smem + 128 * 40);
  } else {
    int cb = bid - 512;
    conv_body(x, srw_bf, sr_b, xred,
              (cb >> 2) * 64, (cb & 3) * 64, smem, smem + 64 * 40);
  }
}

// ---------------------------------------------------------------------------
// MFMA GEMM (standalone): kv (KV_MODE: K row-major + V^T) and proj.
template <bool BF16_OUT, bool HAS_BIAS, bool KV_MODE>
__global__ __launch_bounds__(256) void mfma_gemm(
    const unsigned short* __restrict__ A, const float* __restrict__ W,
    const float* __restrict__ bias, void* __restrict__ Cv,
    void* __restrict__ Vtp, int M, int N, int K, float oscale) {
  __shared__ unsigned short Asb[128 * 40];
  __shared__ unsigned short Bsb[64 * 40];
  const int tid = threadIdx.x;
  const int w = tid >> 6, l = tid & 63, c = l & 15, g = l >> 4;
  const int wr = w >> 1, wc = w & 1;
  const int m0 = blockIdx.y * 128, n0 = blockIdx.x * 64;
  const int ar = tid >> 1, ah = tid & 1;
  const int bn = tid >> 2, bq = tid & 3;

  f32x4 acc[4][2];
#pragma unroll
  for (int mt = 0; mt < 4; ++mt)
#pragma unroll
    for (int nt = 0; nt < 2; ++nt)
#pragma unroll
      for (int r = 0; r < 4; ++r) acc[mt][nt][r] = 0.f;

  for (int k0 = 0; k0 < K; k0 += 32) {
    __syncthreads();
    {
      const unsigned short* asrc = A + (size_t)(m0 + ar) * K + k0 + ah * 16;
      u16x8 a0 = *reinterpret_cast<const u16x8*>(asrc);
      u16x8 a1 = *reinterpret_cast<const u16x8*>(asrc + 8);
      *reinterpret_cast<u16x8*>(&Asb[ar * 40 + ah * 16]) = a0;
      *reinterpret_cast<u16x8*>(&Asb[ar * 40 + ah * 16 + 8]) = a1;
    }
    {
      const float* wsrc = W + (size_t)(n0 + bn) * K + k0 + bq * 8;
      float4 w0 = *reinterpret_cast<const float4*>(wsrc);
      float4 w1 = *reinterpret_cast<const float4*>(wsrc + 4);
      u16x8 wb;
      wb[0] = f2bf(w0.x); wb[1] = f2bf(w0.y); wb[2] = f2bf(w0.z); wb[3] = f2bf(w0.w);
      wb[4] = f2bf(w1.x); wb[5] = f2bf(w1.y); wb[6] = f2bf(w1.z); wb[7] = f2bf(w1.w);
      *reinterpret_cast<u16x8*>(&Bsb[bn * 40 + bq * 8]) = wb;
    }
    __syncthreads();
    bf16x8 af[4], bfr[2];
#pragma unroll
    for (int mt = 0; mt < 4; ++mt)
      af[mt] = *reinterpret_cast<const bf16x8*>(
          &Asb[(wr * 64 + mt * 16 + c) * 40 + g * 8]);
#pragma unroll
    for (int nt = 0; nt < 2; ++nt)
      bfr[nt] = *reinterpret_cast<const bf16x8*>(
          &Bsb[(wc * 32 + nt * 16 + c) * 40 + g * 8]);
#pragma unroll
    for (int mt = 0; mt < 4; ++mt)
#pragma unroll
      for (int nt = 0; nt < 2; ++nt)
        acc[mt][nt] = __builtin_amdgcn_mfma_f32_16x16x32_bf16(
            af[mt], bfr[nt], acc[mt][nt], 0, 0, 0);
  }

#pragma unroll
  for (int mt = 0; mt < 4; ++mt)
#pragma unroll
    for (int nt = 0; nt < 2; ++nt) {
      int row = m0 + wr * 64 + mt * 16 + g * 4;
      int col = n0 + wc * 32 + nt * 16 + c;
      float bv = HAS_BIAS ? bias[col] : 0.f;
#pragma unroll
      for (int r = 0; r < 4; ++r) {
        float v = acc[mt][nt][r] * oscale + bv;
        if (KV_MODE) {
          if (col < 256) {
            ((unsigned short*)Cv)[(size_t)(row + r) * 256 + col] = f2bf(v);
          } else {
            int head = (col - 256) >> 5, d = (col - 256) & 31;
            int rr = row + r;
            ((unsigned short*)Vtp)[
                ((size_t)(((rr >> 10) << 3) + head) * 32 + d) * 1024 +
                (rr & 1023)] = f2bf(v);
          }
        } else if (BF16_OUT) {
          ((unsigned short*)Cv)[(size_t)(row + r) * N + col] = f2bf(v);
        } else {
          ((float*)Cv)[(size_t)(row + r) * N + col] = v;
        }
      }
    }
}

// ---------------------------------------------------------------------------
// LayerNorm over C=256; one wave per row, float4 loads, no LDS/barrier.
__global__ __launch_bounds__(256) void ln_kernel(
    const float* __restrict__ xr, const float* __restrict__ gam,
    const float* __restrict__ bet, unsigned short* __restrict__ xo) {
  const int w = threadIdx.x >> 6, l = threadIdx.x & 63;
  const int row = blockIdx.x * 4 + w;
  float4 v = *reinterpret_cast<const float4*>(xr + (size_t)row * 256 + l * 4);
  float s = (v.x + v.y) + (v.z + v.w);
  float s2 = (v.x * v.x + v.y * v.y) + (v.z * v.z + v.w * v.w);
#pragma unroll
  for (int off = 32; off > 0; off >>= 1) {
    s  += __shfl_xor(s, off, 64);
    s2 += __shfl_xor(s2, off, 64);
  }
  float mean = s * (1.f / 256.f);
  float var = s2 * (1.f / 256.f) - mean * mean;
  float rstd = rsqrtf(var + 1e-5f);
  float4 g = *reinterpret_cast<const float4*>(gam + l * 4);
  float4 bb = *reinterpret_cast<const float4*>(bet + l * 4);
  unsigned short o0 = f2bf((v.x - mean) * rstd * g.x + bb.x);
  unsigned short o1 = f2bf((v.y - mean) * rstd * g.y + bb.y);
  unsigned short o2 = f2bf((v.z - mean) * rstd * g.z + bb.z);
  unsigned short o3 = f2bf((v.w - mean) * rstd * g.w + bb.w);
  unsigned long long pk =
      (unsigned long long)o0 | ((unsigned long long)o1 << 16) |
      ((unsigned long long)o2 << 32) | ((unsigned long long)o3 << 48);
  *reinterpret_cast<unsigned long long*>(xo + (size_t)row * 256 + l * 4) = pk;
}

// ---------------------------------------------------------------------------
// 32x32x16-MFMA flash attention. 2 waves/block (64 q rows), K AND V LDS
// double-buffered (reg prefetch 1 tile ahead), 1 barrier/tile.
// K staged from Kb [4096][256] into [64][36]; V^T staged from Vtg
// [(b*8+h)*32+d][1024] into [32][72]. Q pre-scaled; flat softmax.
__global__ __launch_bounds__(128) void attn_mfma(
    const unsigned short* __restrict__ Qb,
    const unsigned short* __restrict__ Kb,
    const unsigned short* __restrict__ Vtg,
    unsigned short* __restrict__ O) {
  __shared__ __align__(16) unsigned short Kt[2][64][36];
  __shared__ __align__(16) unsigned short Vt[2][32][72];

  const int tid = threadIdx.x;
  const int l = tid & 63;
  const int w = tid >> 6;
  const int q32 = l & 31, hi = l >> 5;
  const int wg = blockIdx.x;
  const int qb = wg & 63, head = (wg >> 6) & 7, b = wg >> 9;
  const int hcol = head << 5;
  const int q0 = (b << 12) + (qb << 6) + (w << 5);

  // Q B-frags (pre-scaled)
  bf16x8 qf[2];
  {
    const unsigned short* qp = Qb + (size_t)(q0 + q32) * 256 + hcol + hi * 8;
    qf[0] = *reinterpret_cast<const bf16x8*>(qp);
    qf[1] = *reinterpret_cast<const bf16x8*>(qp + 16);
  }

  // V staging: thread -> (d = tid>>2, kv chunk = (tid&3)*16).
  const int sd = tid >> 2, skv = (tid & 3) << 4;
  const unsigned short* vtrow =
      Vtg + ((size_t)((b << 3) + head) * 32 + sd) * 1024 + skv;
  // K staging: thread -> (kv row = tid>>1, d half = (tid&1)*16).
  const int kr = tid >> 1, kh = (tid & 1) << 4;
  const unsigned short* ktrow =
      Kb + ((size_t)(b << 10) + kr) * 256 + hcol + kh;

  // prologue: stage tile 0 into buf 0
  {
    u16x8 va = *reinterpret_cast<const u16x8*>(vtrow);
    u16x8 vb = *reinterpret_cast<const u16x8*>(vtrow + 8);
    *reinterpret_cast<u16x8*>(&Vt[0][sd][skv]) = va;
    *reinterpret_cast<u16x8*>(&Vt[0][sd][skv + 8]) = vb;
    u16x8 ka = *reinterpret_cast<const u16x8*>(ktrow);
    u16x8 kb2 = *reinterpret_cast<const u16x8*>(ktrow + 8);
    *reinterpret_cast<u16x8*>(&Kt[0][kr][kh]) = ka;
    *reinterpret_cast<u16x8*>(&Kt[0][kr][kh + 8]) = kb2;
  }

  f32x16 acc;
#pragma unroll
  for (int r = 0; r < 16; ++r) acc[r] = 0.f;
  float lsum = 0.f;

  for (int t = 0; t < 16; ++t) {
    const int cur = t & 1;
    __syncthreads();

    // prefetch next K+V tile into regs (hides under QK+softmax+PV)
    u16x8 nv0, nv1, nk0, nk1;
    if (t < 15) {
      const unsigned short* vp = vtrow + (t + 1) * 64;
      nv0 = *reinterpret_cast<const u16x8*>(vp);
      nv1 = *reinterpret_cast<const u16x8*>(vp + 8);
      const unsigned short* kp = ktrow + (size_t)(t + 1) * 64 * 256;
      nk0 = *reinterpret_cast<const u16x8*>(kp);
      nk1 = *reinterpret_cast<const u16x8*>(kp + 8);
    }

    // ---- QK^T (swapped): S^T[kv][q] = mfma32(K, Q), K from LDS ----
    f32x16 s[2];
    {
      bf16x8 k00 = *reinterpret_cast<const bf16x8*>(&Kt[cur][q32][hi * 8]);
      bf16x8 k01 = *reinterpret_cast<const bf16x8*>(&Kt[cur][q32][hi * 8 + 16]);
      bf16x8 k10 = *reinterpret_cast<const bf16x8*>(&Kt[cur][q32 + 32][hi * 8]);
      bf16x8 k11 = *reinterpret_cast<const bf16x8*>(&Kt[cur][q32 + 32][hi * 8 + 16]);
      f32x16 z;
#pragma unroll
      for (int r = 0; r < 16; ++r) z[r] = 0.f;
      s[0] = __builtin_amdgcn_mfma_f32_32x32x16_bf16(k00, qf[0], z, 0, 0, 0);
      s[0] = __builtin_amdgcn_mfma_f32_32x32x16_bf16(k01, qf[1], s[0], 0, 0, 0);
      s[1] = __builtin_amdgcn_mfma_f32_32x32x16_bf16(k10, qf[0], z, 0, 0, 0);
      s[1] = __builtin_amdgcn_mfma_f32_32x32x16_bf16(k11, qf[1], s[1], 0, 0, 0);
    }

    // ---- softmax + in-register P redistribution + PV ----
#pragma unroll
    for (int kvb = 0; kvb < 2; ++kvb) {
      float p16[16];
#pragma unroll
      for (int r = 0; r < 16; ++r)
        p16[r] = __builtin_amdgcn_exp2f(s[kvb][r]);
      float s0 = (p16[0] + p16[1]) + (p16[2] + p16[3]);
      float s1 = (p16[4] + p16[5]) + (p16[6] + p16[7]);
      float s2 = (p16[8] + p16[9]) + (p16[10] + p16[11]);
      float s3 = (p16[12] + p16[13]) + (p16[14] + p16[15]);
      lsum += (s0 + s1) + (s2 + s3);
      unsigned A[8];
#pragma unroll
      for (int i = 0; i < 8; ++i) {
        unsigned o;
        asm("v_cvt_pk_bf16_f32 %0, %1, %2"
            : "=v"(o) : "v"(p16[2 * i]), "v"(p16[2 * i + 1]));
        A[i] = o;
      }
      u32x2v r02 = __builtin_amdgcn_permlane32_swap(A[0], A[2], false, false);
      u32x2v r13 = __builtin_amdgcn_permlane32_swap(A[1], A[3], false, false);
      u32x2v r46 = __builtin_amdgcn_permlane32_swap(A[4], A[6], false, false);
      u32x2v r57 = __builtin_amdgcn_permlane32_swap(A[5], A[7], false, false);
      u32x4v pk0 = {r02[0], r13[0], r02[1], r13[1]};
      u32x4v pk1 = {r46[0], r57[0], r46[1], r57[1]};
      bf16x8 pf0 = __builtin_bit_cast(bf16x8, pk0);
      bf16x8 pf1 = __builtin_bit_cast(bf16x8, pk1);
      const unsigned short* vrow = &Vt[cur][q32][kvb * 32 + hi * 8];
      bf16x8 vf0 = *reinterpret_cast<const bf16x8*>(vrow);
      bf16x8 vf1 = *reinterpret_cast<const bf16x8*>(vrow + 16);
      acc = __builtin_amdgcn_mfma_f32_32x32x16_bf16(vf0, pf0, acc, 0, 0, 0);
      acc = __builtin_amdgcn_mfma_f32_32x32x16_bf16(vf1, pf1, acc, 0, 0, 0);
    }

    // ---- write prefetched K+V into the other buffer ----
    if (t < 15) {
      *reinterpret_cast<u16x8*>(&Vt[cur ^ 1][sd][skv]) = nv0;
      *reinterpret_cast<u16x8*>(&Vt[cur ^ 1][sd][skv + 8]) = nv1;
      *reinterpret_cast<u16x8*>(&Kt[cur ^ 1][kr][kh]) = nk0;
      *reinterpret_cast<u16x8*>(&Kt[cur ^ 1][kr][kh + 8]) = nk1;
    }
  }

  // ---- epilogue: O^T[d][q] regs -> O[q][d] bf16 ----
  lsum += __shfl_xor(lsum, 32, 64);
  float inv = 1.f / lsum;
  unsigned short* orow = O + (size_t)(q0 + q32) * 256 + hcol;
#pragma unroll
  for (int rb = 0; rb < 4; ++rb) {
    const int d0 = rb * 8 + hi * 4;
    float a0 = acc[rb * 4 + 0] * inv, a1 = acc[rb * 4 + 1] * inv;
    float a2 = acc[rb * 4 + 2] * inv, a3 = acc[rb * 4 + 3] * inv;
    unsigned w0, w1;
    asm("v_cvt_pk_bf16_f32 %0, %1, %2" : "=v"(w0) : "v"(a0), "v"(a1));
    asm("v_cvt_pk_bf16_f32 %0, %1, %2" : "=v"(w1) : "v"(a2), "v"(a3));
    unsigned long long pk = (unsigned long long)w0 | ((unsigned long long)w1 << 32);
    *reinterpret_cast<unsigned long long*>(orow + d0) = pk;
  }
}

// ---------------------------------------------------------------------------
extern "C" void kernel_launch(void* const* d_in, const int* in_sizes, int n_in,
                              void* d_out, int out_size, void* d_ws,
                              size_t ws_size, hipStream_t stream) {
  const float* x      = (const float*)d_in[0];
  const float* sr_w   = (const float*)d_in[3];
  const float* sr_b   = (const float*)d_in[4];
  const float* ln_g   = (const float*)d_in[5];
  const float* ln_b   = (const float*)d_in[6];
  const float* q_w    = (const float*)d_in[7];
  const float* kv_w   = (const float*)d_in[8];
  const float* proj_w = (const float*)d_in[9];
  const float* proj_b = (const float*)d_in[10];
  float* out = (float*)d_out;

  char* ws = (char*)d_ws;
  unsigned short* q_bf    = (unsigned short*)(ws);               // 8 MB
  unsigned short* srw_bf  = (unsigned short*)(ws + 8388608);     // 512 KB
  float*          xred    = (float*)(ws + 8912896);              // 4 MB
  unsigned short* x_ln    = (unsigned short*)(ws + 13107200);    // 2 MB
  unsigned short* k_buf   = (unsigned short*)(ws + 15204352);    // 2 MB
  unsigned short* vt_buf  = (unsigned short*)(ws + 17301504);    // 2 MB
  unsigned short* attn_bf = (unsigned short*)(ws + 19398656);    // 8 MB

  const float qscale = 0.25506975154985854f;  // (1/sqrt(32)) * log2(e)

  // 1. prep: sr_w permute
  prep_kernel<<<256, 256, 0, stream>>>(sr_w, srw_bf);
  // 2. fused q GEMM (512 blocks) + conv (256 blocks), both staging f32 x
  qconv_kernel<<<768, 256, 0, stream>>>(
      x, q_w, q_bf, srw_bf, sr_b, xred, qscale);
  // 3. LayerNorm (bf16 out), 1 wave/row
  ln_kernel<<<1024, 256, 0, stream>>>(xred, ln_g, ln_b, x_ln);
  // 4. kv = x_ln @ kv_w^T -> K row-major + V transposed
  mfma_gemm<true, false, true><<<dim3(8, 32), 256, 0, stream>>>(
      x_ln, kv_w, nullptr, k_buf, vt_buf, 4096, 512, 256, 1.0f);
  // 5. attention (bf16 out), K+V LDS double-buffered
  attn_mfma<<<2048, 128, 0, stream>>>(q_bf, k_buf, vt_buf, attn_bf);
  // 6. out = attn_o @ proj_w^T + proj_b (f32)
  mfma_gemm<false, true, false><<<dim3(4, 128), 256, 0, stream>>>(
      attn_bf, proj_w, proj_b, out, nullptr, 16384, 256, 256, 1.0f);
}

// Round 11
// 92.336 us; speedup vs baseline: 1.4955x; 1.0436x over previous
//
#include <hip/hip_runtime.h>
#include <hip/hip_bf16.h>

// SequenceReductionAttention (PVT-style SRA).
// B=4, N=4096 (64x64), C=256, heads=8, d=32, SR=2 -> N'=1024 (32x32).
//
// Round 11:
//  - proj GEMM retiled 64x64 (1024 blocks) -- latency-bound small-K GEMM
//    wants width, not per-block depth.
//  - attn blocks 2->4 waves (1024 blocks, same 4096 waves, same LDS):
//    staging amortized over 4 waves (per-thread staging halves). Loop body
//    unchanged from verified R10 kernel.

typedef __attribute__((ext_vector_type(8))) short bf16x8;
typedef __attribute__((ext_vector_type(8))) unsigned short u16x8;
typedef __attribute__((ext_vector_type(4))) float f32x4;
typedef __attribute__((ext_vector_type(16))) float f32x16;
typedef __attribute__((ext_vector_type(2))) unsigned u32x2v;
typedef __attribute__((ext_vector_type(4))) unsigned u32x4v;

__device__ inline unsigned short f2bf(float f) {
  unsigned u = __float_as_uint(f);
  u += 0x7fffu + ((u >> 16) & 1u);
  return (unsigned short)(u >> 16);
}

// ---------------------------------------------------------------------------
// prep: permute sr_w [256 o][256 ci][4 tap] f32 -> [256 o][4 tap][256 ci] bf16.
__global__ __launch_bounds__(256) void prep_kernel(
    const float* __restrict__ srw, unsigned short* __restrict__ srw_bf) {
  const int o = blockIdx.x, t = threadIdx.x;
  float4 v = reinterpret_cast<const float4*>(srw + (size_t)o * 1024)[t];
  srw_bf[(size_t)o * 1024 + 0 * 256 + t] = f2bf(v.x);
  srw_bf[(size_t)o * 1024 + 1 * 256 + t] = f2bf(v.y);
  srw_bf[(size_t)o * 1024 + 2 * 256 + t] = f2bf(v.z);
  srw_bf[(size_t)o * 1024 + 3 * 256 + t] = f2bf(v.w);
}

// ---------------------------------------------------------------------------
// GEMM body: C[M,N](bf16) = (A[M,K]f32->bf16 @ W[N,K]f32->bf16 ^T) * oscale.
// 128x64 tile, BK=32, 4 waves.
__device__ __forceinline__ void gemm_body_q(
    const float* __restrict__ Af, const float* __restrict__ W,
    unsigned short* __restrict__ C, int K, int N, float oscale,
    int m0, int n0, unsigned short* Asb, unsigned short* Bsb) {
  const int tid = threadIdx.x;
  const int w = tid >> 6, l = tid & 63, c = l & 15, g = l >> 4;
  const int wr = w >> 1, wc = w & 1;
  const int ar = tid >> 1, ah = tid & 1;
  const int bn = tid >> 2, bq = tid & 3;

  f32x4 acc[4][2];
#pragma unroll
  for (int mt = 0; mt < 4; ++mt)
#pragma unroll
    for (int nt = 0; nt < 2; ++nt)
#pragma unroll
      for (int r = 0; r < 4; ++r) acc[mt][nt][r] = 0.f;

  for (int k0 = 0; k0 < K; k0 += 32) {
    __syncthreads();
    {
      const float* asrc = Af + (size_t)(m0 + ar) * K + k0 + ah * 16;
      float4 a0 = *reinterpret_cast<const float4*>(asrc);
      float4 a1 = *reinterpret_cast<const float4*>(asrc + 4);
      float4 a2 = *reinterpret_cast<const float4*>(asrc + 8);
      float4 a3 = *reinterpret_cast<const float4*>(asrc + 12);
      u16x8 w0, w1;
      w0[0] = f2bf(a0.x); w0[1] = f2bf(a0.y); w0[2] = f2bf(a0.z); w0[3] = f2bf(a0.w);
      w0[4] = f2bf(a1.x); w0[5] = f2bf(a1.y); w0[6] = f2bf(a1.z); w0[7] = f2bf(a1.w);
      w1[0] = f2bf(a2.x); w1[1] = f2bf(a2.y); w1[2] = f2bf(a2.z); w1[3] = f2bf(a2.w);
      w1[4] = f2bf(a3.x); w1[5] = f2bf(a3.y); w1[6] = f2bf(a3.z); w1[7] = f2bf(a3.w);
      *reinterpret_cast<u16x8*>(&Asb[ar * 40 + ah * 16]) = w0;
      *reinterpret_cast<u16x8*>(&Asb[ar * 40 + ah * 16 + 8]) = w1;
    }
    {
      const float* wsrc = W + (size_t)(n0 + bn) * K + k0 + bq * 8;
      float4 w0 = *reinterpret_cast<const float4*>(wsrc);
      float4 w1 = *reinterpret_cast<const float4*>(wsrc + 4);
      u16x8 wb;
      wb[0] = f2bf(w0.x); wb[1] = f2bf(w0.y); wb[2] = f2bf(w0.z); wb[3] = f2bf(w0.w);
      wb[4] = f2bf(w1.x); wb[5] = f2bf(w1.y); wb[6] = f2bf(w1.z); wb[7] = f2bf(w1.w);
      *reinterpret_cast<u16x8*>(&Bsb[bn * 40 + bq * 8]) = wb;
    }
    __syncthreads();
    bf16x8 af[4], bfr[2];
#pragma unroll
    for (int mt = 0; mt < 4; ++mt)
      af[mt] = *reinterpret_cast<const bf16x8*>(
          &Asb[(wr * 64 + mt * 16 + c) * 40 + g * 8]);
#pragma unroll
    for (int nt = 0; nt < 2; ++nt)
      bfr[nt] = *reinterpret_cast<const bf16x8*>(
          &Bsb[(wc * 32 + nt * 16 + c) * 40 + g * 8]);
#pragma unroll
    for (int mt = 0; mt < 4; ++mt)
#pragma unroll
      for (int nt = 0; nt < 2; ++nt)
        acc[mt][nt] = __builtin_amdgcn_mfma_f32_16x16x32_bf16(
            af[mt], bfr[nt], acc[mt][nt], 0, 0, 0);
  }

#pragma unroll
  for (int mt = 0; mt < 4; ++mt)
#pragma unroll
    for (int nt = 0; nt < 2; ++nt) {
      int row = m0 + wr * 64 + mt * 16 + g * 4;
      int col = n0 + wc * 32 + nt * 16 + c;
#pragma unroll
      for (int r = 0; r < 4; ++r)
        C[(size_t)(row + r) * N + col] = f2bf(acc[mt][nt][r] * oscale);
    }
}

// ---------------------------------------------------------------------------
// Conv body: 64x64 tile, tap-major K=1024, f32 x cast on stage.
__device__ __forceinline__ void conv_body(
    const float* __restrict__ Xf, const unsigned short* __restrict__ Wp,
    const float* __restrict__ bias, float* __restrict__ C,
    int m0, int n0, unsigned short* Asb, unsigned short* Bsb) {
  const int tid = threadIdx.x;
  const int w = tid >> 6, l = tid & 63, c = l & 15, g = l >> 4;
  const int wr = w >> 1, wc = w & 1;
  const int sr = tid >> 2, sh = tid & 3;

  int base[4];
  {
    int row = m0 + sr;
    int b = row >> 10, o = row & 1023, oh = o >> 5, ow = o & 31;
#pragma unroll
    for (int tap = 0; tap < 4; ++tap) {
      int n = ((oh << 1) + (tap >> 1)) * 64 + (ow << 1) + (tap & 1);
      base[tap] = ((b << 12) + n) << 8;
    }
  }

  f32x4 acc[2][2];
#pragma unroll
  for (int mt = 0; mt < 2; ++mt)
#pragma unroll
    for (int nt = 0; nt < 2; ++nt)
#pragma unroll
      for (int r = 0; r < 4; ++r) acc[mt][nt][r] = 0.f;

  for (int k0 = 0; k0 < 1024; k0 += 32) {
    const int tap = k0 >> 8, ci0 = (k0 & 255) + sh * 8;
    __syncthreads();
    {
      const float* xp = Xf + base[tap] + ci0;
      float4 a0 = *reinterpret_cast<const float4*>(xp);
      float4 a1 = *reinterpret_cast<const float4*>(xp + 4);
      u16x8 av;
      av[0] = f2bf(a0.x); av[1] = f2bf(a0.y); av[2] = f2bf(a0.z); av[3] = f2bf(a0.w);
      av[4] = f2bf(a1.x); av[5] = f2bf(a1.y); av[6] = f2bf(a1.z); av[7] = f2bf(a1.w);
      *reinterpret_cast<u16x8*>(&Asb[sr * 40 + sh * 8]) = av;
    }
    u16x8 wv = *reinterpret_cast<const u16x8*>(
        &Wp[(size_t)(n0 + sr) * 1024 + k0 + sh * 8]);
    *reinterpret_cast<u16x8*>(&Bsb[sr * 40 + sh * 8]) = wv;
    __syncthreads();
    bf16x8 af[2], bfr[2];
#pragma unroll
    for (int mt = 0; mt < 2; ++mt)
      af[mt] = *reinterpret_cast<const bf16x8*>(
          &Asb[(wr * 32 + mt * 16 + c) * 40 + g * 8]);
#pragma unroll
    for (int nt = 0; nt < 2; ++nt)
      bfr[nt] = *reinterpret_cast<const bf16x8*>(
          &Bsb[(wc * 32 + nt * 16 + c) * 40 + g * 8]);
#pragma unroll
    for (int mt = 0; mt < 2; ++mt)
#pragma unroll
      for (int nt = 0; nt < 2; ++nt)
        acc[mt][nt] = __builtin_amdgcn_mfma_f32_16x16x32_bf16(
            af[mt], bfr[nt], acc[mt][nt], 0, 0, 0);
  }

#pragma unroll
  for (int mt = 0; mt < 2; ++mt)
#pragma unroll
    for (int nt = 0; nt < 2; ++nt) {
      int row = m0 + wr * 32 + mt * 16 + g * 4;
      int col = n0 + wc * 32 + nt * 16 + c;
      float bv = bias[col];
#pragma unroll
      for (int r = 0; r < 4; ++r)
        C[(size_t)(row + r) * 256 + col] = acc[mt][nt][r] + bv;
    }
}

// ---------------------------------------------------------------------------
// Fused dispatch: blocks [0,512) = q GEMM, blocks [512,768) = conv.
__global__ __launch_bounds__(256) void qconv_kernel(
    const float* __restrict__ x, const float* __restrict__ q_w,
    unsigned short* __restrict__ q_bf, const unsigned short* __restrict__ srw_bf,
    const float* __restrict__ sr_b, float* __restrict__ xred, float qscale) {
  __shared__ unsigned short smem[128 * 40 + 64 * 40];
  const int bid = blockIdx.x;
  if (bid < 512) {
    gemm_body_q(x, q_w, q_bf, 256, 256, qscale,
                (bid >> 2) * 128, (bid & 3) * 64, smem, smem + 128 * 40);
  } else {
    int cb = bid - 512;
    conv_body(x, srw_bf, sr_b, xred,
              (cb >> 2) * 64, (cb & 3) * 64, smem, smem + 64 * 40);
  }
}

// ---------------------------------------------------------------------------
// kv GEMM: 128x64 tile, KV_MODE epilogue (K row-major + V^T).
__global__ __launch_bounds__(256) void kv_gemm(
    const unsigned short* __restrict__ A, const float* __restrict__ W,
    unsigned short* __restrict__ Kb, unsigned short* __restrict__ Vtp) {
  __shared__ unsigned short Asb[128 * 40];
  __shared__ unsigned short Bsb[64 * 40];
  const int tid = threadIdx.x;
  const int w = tid >> 6, l = tid & 63, c = l & 15, g = l >> 4;
  const int wr = w >> 1, wc = w & 1;
  const int m0 = blockIdx.y * 128, n0 = blockIdx.x * 64;
  const int ar = tid >> 1, ah = tid & 1;
  const int bn = tid >> 2, bq = tid & 3;
  const int K = 256;

  f32x4 acc[4][2];
#pragma unroll
  for (int mt = 0; mt < 4; ++mt)
#pragma unroll
    for (int nt = 0; nt < 2; ++nt)
#pragma unroll
      for (int r = 0; r < 4; ++r) acc[mt][nt][r] = 0.f;

  for (int k0 = 0; k0 < K; k0 += 32) {
    __syncthreads();
    {
      const unsigned short* asrc = A + (size_t)(m0 + ar) * K + k0 + ah * 16;
      u16x8 a0 = *reinterpret_cast<const u16x8*>(asrc);
      u16x8 a1 = *reinterpret_cast<const u16x8*>(asrc + 8);
      *reinterpret_cast<u16x8*>(&Asb[ar * 40 + ah * 16]) = a0;
      *reinterpret_cast<u16x8*>(&Asb[ar * 40 + ah * 16 + 8]) = a1;
    }
    {
      const float* wsrc = W + (size_t)(n0 + bn) * K + k0 + bq * 8;
      float4 w0 = *reinterpret_cast<const float4*>(wsrc);
      float4 w1 = *reinterpret_cast<const float4*>(wsrc + 4);
      u16x8 wb;
      wb[0] = f2bf(w0.x); wb[1] = f2bf(w0.y); wb[2] = f2bf(w0.z); wb[3] = f2bf(w0.w);
      wb[4] = f2bf(w1.x); wb[5] = f2bf(w1.y); wb[6] = f2bf(w1.z); wb[7] = f2bf(w1.w);
      *reinterpret_cast<u16x8*>(&Bsb[bn * 40 + bq * 8]) = wb;
    }
    __syncthreads();
    bf16x8 af[4], bfr[2];
#pragma unroll
    for (int mt = 0; mt < 4; ++mt)
      af[mt] = *reinterpret_cast<const bf16x8*>(
          &Asb[(wr * 64 + mt * 16 + c) * 40 + g * 8]);
#pragma unroll
    for (int nt = 0; nt < 2; ++nt)
      bfr[nt] = *reinterpret_cast<const bf16x8*>(
          &Bsb[(wc * 32 + nt * 16 + c) * 40 + g * 8]);
#pragma unroll
    for (int mt = 0; mt < 4; ++mt)
#pragma unroll
      for (int nt = 0; nt < 2; ++nt)
        acc[mt][nt] = __builtin_amdgcn_mfma_f32_16x16x32_bf16(
            af[mt], bfr[nt], acc[mt][nt], 0, 0, 0);
  }

#pragma unroll
  for (int mt = 0; mt < 4; ++mt)
#pragma unroll
    for (int nt = 0; nt < 2; ++nt) {
      int row = m0 + wr * 64 + mt * 16 + g * 4;
      int col = n0 + wc * 32 + nt * 16 + c;
#pragma unroll
      for (int r = 0; r < 4; ++r) {
        float v = acc[mt][nt][r];
        if (col < 256) {
          Kb[(size_t)(row + r) * 256 + col] = f2bf(v);
        } else {
          int head = (col - 256) >> 5, d = (col - 256) & 31;
          int rr = row + r;
          Vtp[((size_t)(((rr >> 10) << 3) + head) * 32 + d) * 1024 +
              (rr & 1023)] = f2bf(v);
        }
      }
    }
}

// ---------------------------------------------------------------------------
// proj GEMM: out[16384,256] f32 = attn_bf @ proj_w^T + proj_b.
// 64x64 tile, 4 waves, 1024 blocks (latency-bound small-K wants width).
__global__ __launch_bounds__(256) void proj_gemm(
    const unsigned short* __restrict__ A, const float* __restrict__ W,
    const float* __restrict__ bias, float* __restrict__ C) {
  __shared__ unsigned short Asb[64 * 40];
  __shared__ unsigned short Bsb[64 * 40];
  const int tid = threadIdx.x;
  const int w = tid >> 6, l = tid & 63, c = l & 15, g = l >> 4;
  const int wr = w >> 1, wc = w & 1;
  const int m0 = blockIdx.y * 64, n0 = blockIdx.x * 64;
  const int sr = tid >> 2, sh = tid & 3;

  f32x4 acc[2][2];
#pragma unroll
  for (int mt = 0; mt < 2; ++mt)
#pragma unroll
    for (int nt = 0; nt < 2; ++nt)
#pragma unroll
      for (int r = 0; r < 4; ++r) acc[mt][nt][r] = 0.f;

  for (int k0 = 0; k0 < 256; k0 += 32) {
    __syncthreads();
    {
      u16x8 av = *reinterpret_cast<const u16x8*>(
          &A[(size_t)(m0 + sr) * 256 + k0 + sh * 8]);
      *reinterpret_cast<u16x8*>(&Asb[sr * 40 + sh * 8]) = av;
    }
    {
      const float* wsrc = W + (size_t)(n0 + sr) * 256 + k0 + sh * 8;
      float4 w0 = *reinterpret_cast<const float4*>(wsrc);
      float4 w1 = *reinterpret_cast<const float4*>(wsrc + 4);
      u16x8 wb;
      wb[0] = f2bf(w0.x); wb[1] = f2bf(w0.y); wb[2] = f2bf(w0.z); wb[3] = f2bf(w0.w);
      wb[4] = f2bf(w1.x); wb[5] = f2bf(w1.y); wb[6] = f2bf(w1.z); wb[7] = f2bf(w1.w);
      *reinterpret_cast<u16x8*>(&Bsb[sr * 40 + sh * 8]) = wb;
    }
    __syncthreads();
    bf16x8 af[2], bfr[2];
#pragma unroll
    for (int mt = 0; mt < 2; ++mt)
      af[mt] = *reinterpret_cast<const bf16x8*>(
          &Asb[(wr * 32 + mt * 16 + c) * 40 + g * 8]);
#pragma unroll
    for (int nt = 0; nt < 2; ++nt)
      bfr[nt] = *reinterpret_cast<const bf16x8*>(
          &Bsb[(wc * 32 + nt * 16 + c) * 40 + g * 8]);
#pragma unroll
    for (int mt = 0; mt < 2; ++mt)
#pragma unroll
      for (int nt = 0; nt < 2; ++nt)
        acc[mt][nt] = __builtin_amdgcn_mfma_f32_16x16x32_bf16(
            af[mt], bfr[nt], acc[mt][nt], 0, 0, 0);
  }

#pragma unroll
  for (int mt = 0; mt < 2; ++mt)
#pragma unroll
    for (int nt = 0; nt < 2; ++nt) {
      int row = m0 + wr * 32 + mt * 16 + g * 4;
      int col = n0 + wc * 32 + nt * 16 + c;
      float bv = bias[col];
#pragma unroll
      for (int r = 0; r < 4; ++r)
        C[(size_t)(row + r) * 256 + col] = acc[mt][nt][r] + bv;
    }
}

// ---------------------------------------------------------------------------
// LayerNorm over C=256; one wave per row, float4 loads, no LDS/barrier.
__global__ __launch_bounds__(256) void ln_kernel(
    const float* __restrict__ xr, const float* __restrict__ gam,
    const float* __restrict__ bet, unsigned short* __restrict__ xo) {
  const int w = threadIdx.x >> 6, l = threadIdx.x & 63;
  const int row = blockIdx.x * 4 + w;
  float4 v = *reinterpret_cast<const float4*>(xr + (size_t)row * 256 + l * 4);
  float s = (v.x + v.y) + (v.z + v.w);
  float s2 = (v.x * v.x + v.y * v.y) + (v.z * v.z + v.w * v.w);
#pragma unroll
  for (int off = 32; off > 0; off >>= 1) {
    s  += __shfl_xor(s, off, 64);
    s2 += __shfl_xor(s2, off, 64);
  }
  float mean = s * (1.f / 256.f);
  float var = s2 * (1.f / 256.f) - mean * mean;
  float rstd = rsqrtf(var + 1e-5f);
  float4 g = *reinterpret_cast<const float4*>(gam + l * 4);
  float4 bb = *reinterpret_cast<const float4*>(bet + l * 4);
  unsigned short o0 = f2bf((v.x - mean) * rstd * g.x + bb.x);
  unsigned short o1 = f2bf((v.y - mean) * rstd * g.y + bb.y);
  unsigned short o2 = f2bf((v.z - mean) * rstd * g.z + bb.z);
  unsigned short o3 = f2bf((v.w - mean) * rstd * g.w + bb.w);
  unsigned long long pk =
      (unsigned long long)o0 | ((unsigned long long)o1 << 16) |
      ((unsigned long long)o2 << 32) | ((unsigned long long)o3 << 48);
  *reinterpret_cast<unsigned long long*>(xo + (size_t)row * 256 + l * 4) = pk;
}

// ---------------------------------------------------------------------------
// 32x32x16-MFMA flash attention. 4 waves/block (128 q rows), K+V LDS
// double-buffered shared by all 4 waves (per-thread staging = one u16x8
// each for K and V), 1 barrier/tile. Loop body identical to R10.
__global__ __launch_bounds__(256) void attn_mfma(
    const unsigned short* __restrict__ Qb,
    const unsigned short* __restrict__ Kb,
    const unsigned short* __restrict__ Vtg,
    unsigned short* __restrict__ O) {
  __shared__ __align__(16) unsigned short Kt[2][64][36];
  __shared__ __align__(16) unsigned short Vt[2][32][72];

  const int tid = threadIdx.x;
  const int l = tid & 63;
  const int w = tid >> 6;
  const int q32 = l & 31, hi = l >> 5;
  const int wg = blockIdx.x;
  const int qb = wg & 31, head = (wg >> 5) & 7, b = wg >> 8;
  const int hcol = head << 5;
  const int q0 = (b << 12) + (qb << 7) + (w << 5);

  // Q B-frags (pre-scaled)
  bf16x8 qf[2];
  {
    const unsigned short* qp = Qb + (size_t)(q0 + q32) * 256 + hcol + hi * 8;
    qf[0] = *reinterpret_cast<const bf16x8*>(qp);
    qf[1] = *reinterpret_cast<const bf16x8*>(qp + 16);
  }

  // V staging: 256 threads -> (d = tid>>3, kv chunk = (tid&7)*8), one u16x8.
  const int sd = tid >> 3, skv = (tid & 7) << 3;
  const unsigned short* vtrow =
      Vtg + ((size_t)((b << 3) + head) * 32 + sd) * 1024 + skv;
  // K staging: 256 threads -> (kv row = tid>>2, d chunk = (tid&3)*8).
  const int kr = tid >> 2, kh = (tid & 3) << 3;
  const unsigned short* ktrow =
      Kb + ((size_t)(b << 10) + kr) * 256 + hcol + kh;

  // prologue: stage tile 0 into buf 0
  {
    u16x8 va = *reinterpret_cast<const u16x8*>(vtrow);
    *reinterpret_cast<u16x8*>(&Vt[0][sd][skv]) = va;
    u16x8 ka = *reinterpret_cast<const u16x8*>(ktrow);
    *reinterpret_cast<u16x8*>(&Kt[0][kr][kh]) = ka;
  }

  f32x16 acc;
#pragma unroll
  for (int r = 0; r < 16; ++r) acc[r] = 0.f;
  float lsum = 0.f;

  for (int t = 0; t < 16; ++t) {
    const int cur = t & 1;
    __syncthreads();

    // prefetch next K+V tile into regs (hides under QK+softmax+PV)
    u16x8 nv0, nk0;
    if (t < 15) {
      nv0 = *reinterpret_cast<const u16x8*>(vtrow + (t + 1) * 64);
      nk0 = *reinterpret_cast<const u16x8*>(ktrow + (size_t)(t + 1) * 64 * 256);
    }

    // ---- QK^T (swapped): S^T[kv][q] = mfma32(K, Q), K from LDS ----
    f32x16 s[2];
    {
      bf16x8 k00 = *reinterpret_cast<const bf16x8*>(&Kt[cur][q32][hi * 8]);
      bf16x8 k01 = *reinterpret_cast<const bf16x8*>(&Kt[cur][q32][hi * 8 + 16]);
      bf16x8 k10 = *reinterpret_cast<const bf16x8*>(&Kt[cur][q32 + 32][hi * 8]);
      bf16x8 k11 = *reinterpret_cast<const bf16x8*>(&Kt[cur][q32 + 32][hi * 8 + 16]);
      f32x16 z;
#pragma unroll
      for (int r = 0; r < 16; ++r) z[r] = 0.f;
      s[0] = __builtin_amdgcn_mfma_f32_32x32x16_bf16(k00, qf[0], z, 0, 0, 0);
      s[0] = __builtin_amdgcn_mfma_f32_32x32x16_bf16(k01, qf[1], s[0], 0, 0, 0);
      s[1] = __builtin_amdgcn_mfma_f32_32x32x16_bf16(k10, qf[0], z, 0, 0, 0);
      s[1] = __builtin_amdgcn_mfma_f32_32x32x16_bf16(k11, qf[1], s[1], 0, 0, 0);
    }

    // ---- softmax + in-register P redistribution + PV ----
#pragma unroll
    for (int kvb = 0; kvb < 2; ++kvb) {
      float p16[16];
#pragma unroll
      for (int r = 0; r < 16; ++r)
        p16[r] = __builtin_amdgcn_exp2f(s[kvb][r]);
      float s0 = (p16[0] + p16[1]) + (p16[2] + p16[3]);
      float s1 = (p16[4] + p16[5]) + (p16[6] + p16[7]);
      float s2 = (p16[8] + p16[9]) + (p16[10] + p16[11]);
      float s3 = (p16[12] + p16[13]) + (p16[14] + p16[15]);
      lsum += (s0 + s1) + (s2 + s3);
      unsigned A[8];
#pragma unroll
      for (int i = 0; i < 8; ++i) {
        unsigned o;
        asm("v_cvt_pk_bf16_f32 %0, %1, %2"
            : "=v"(o) : "v"(p16[2 * i]), "v"(p16[2 * i + 1]));
        A[i] = o;
      }
      u32x2v r02 = __builtin_amdgcn_permlane32_swap(A[0], A[2], false, false);
      u32x2v r13 = __builtin_amdgcn_permlane32_swap(A[1], A[3], false, false);
      u32x2v r46 = __builtin_amdgcn_permlane32_swap(A[4], A[6], false, false);
      u32x2v r57 = __builtin_amdgcn_permlane32_swap(A[5], A[7], false, false);
      u32x4v pk0 = {r02[0], r13[0], r02[1], r13[1]};
      u32x4v pk1 = {r46[0], r57[0], r46[1], r57[1]};
      bf16x8 pf0 = __builtin_bit_cast(bf16x8, pk0);
      bf16x8 pf1 = __builtin_bit_cast(bf16x8, pk1);
      const unsigned short* vrow = &Vt[cur][q32][kvb * 32 + hi * 8];
      bf16x8 vf0 = *reinterpret_cast<const bf16x8*>(vrow);
      bf16x8 vf1 = *reinterpret_cast<const bf16x8*>(vrow + 16);
      acc = __builtin_amdgcn_mfma_f32_32x32x16_bf16(vf0, pf0, acc, 0, 0, 0);
      acc = __builtin_amdgcn_mfma_f32_32x32x16_bf16(vf1, pf1, acc, 0, 0, 0);
    }

    // ---- write prefetched K+V into the other buffer ----
    if (t < 15) {
      *reinterpret_cast<u16x8*>(&Vt[cur ^ 1][sd][skv]) = nv0;
      *reinterpret_cast<u16x8*>(&Kt[cur ^ 1][kr][kh]) = nk0;
    }
  }

  // ---- epilogue: O^T[d][q] regs -> O[q][d] bf16 ----
  lsum += __shfl_xor(lsum, 32, 64);
  float inv = 1.f / lsum;
  unsigned short* orow = O + (size_t)(q0 + q32) * 256 + hcol;
#pragma unroll
  for (int rb = 0; rb < 4; ++rb) {
    const int d0 = rb * 8 + hi * 4;
    float a0 = acc[rb * 4 + 0] * inv, a1 = acc[rb * 4 + 1] * inv;
    float a2 = acc[rb * 4 + 2] * inv, a3 = acc[rb * 4 + 3] * inv;
    unsigned w0, w1;
    asm("v_cvt_pk_bf16_f32 %0, %1, %2" : "=v"(w0) : "v"(a0), "v"(a1));
    asm("v_cvt_pk_bf16_f32 %0, %1, %2" : "=v"(w1) : "v"(a2), "v"(a3));
    unsigned long long pk = (unsigned long long)w0 | ((unsigned long long)w1 << 32);
    *reinterpret_cast<unsigned long long*>(orow + d0) = pk;
  }
}

// ---------------------------------------------------------------------------
extern "C" void kernel_launch(void* const* d_in, const int* in_sizes, int n_in,
                              void* d_out, int out_size, void* d_ws,
                              size_t ws_size, hipStream_t stream) {
  const float* x      = (const float*)d_in[0];
  const float* sr_w   = (const float*)d_in[3];
  const float* sr_b   = (const float*)d_in[4];
  const float* ln_g   = (const float*)d_in[5];
  const float* ln_b   = (const float*)d_in[6];
  const float* q_w    = (const float*)d_in[7];
  const float* kv_w   = (const float*)d_in[8];
  const float* proj_w = (const float*)d_in[9];
  const float* proj_b = (const float*)d_in[10];
  float* out = (float*)d_out;

  char* ws = (char*)d_ws;
  unsigned short* q_bf    = (unsigned short*)(ws);               // 8 MB
  unsigned short* srw_bf  = (unsigned short*)(ws + 8388608);     // 512 KB
  float*          xred    = (float*)(ws + 8912896);              // 4 MB
  unsigned short* x_ln    = (unsigned short*)(ws + 13107200);    // 2 MB
  unsigned short* k_buf   = (unsigned short*)(ws + 15204352);    // 2 MB
  unsigned short* vt_buf  = (unsigned short*)(ws + 17301504);    // 2 MB
  unsigned short* attn_bf = (unsigned short*)(ws + 19398656);    // 8 MB

  const float qscale = 0.25506975154985854f;  // (1/sqrt(32)) * log2(e)

  // 1. prep: sr_w permute
  prep_kernel<<<256, 256, 0, stream>>>(sr_w, srw_bf);
  // 2. fused q GEMM (512 blocks) + conv (256 blocks), both staging f32 x
  qconv_kernel<<<768, 256, 0, stream>>>(
      x, q_w, q_bf, srw_bf, sr_b, xred, qscale);
  // 3. LayerNorm (bf16 out), 1 wave/row
  ln_kernel<<<1024, 256, 0, stream>>>(xred, ln_g, ln_b, x_ln);
  // 4. kv = x_ln @ kv_w^T -> K row-major + V transposed
  kv_gemm<<<dim3(8, 32), 256, 0, stream>>>(x_ln, kv_w, k_buf, vt_buf);
  // 5. attention (bf16 out), 4-wave blocks, K+V LDS double-buffered
  attn_mfma<<<1024, 256, 0, stream>>>(q_bf, k_buf, vt_buf, attn_bf);
  // 6. out = attn_o @ proj_w^T + proj_b (f32), 64x64 x 1024 blocks
  proj_gemm<<<dim3(4, 256), 256, 0, stream>>>(attn_bf, proj_w, proj_b, out);
}

// Round 12
// 88.786 us; speedup vs baseline: 1.5553x; 1.0400x over previous
//
#include <hip/hip_runtime.h>
#include <hip/hip_bf16.h>

// SequenceReductionAttention (PVT-style SRA).
// B=4, N=4096 (64x64), C=256, heads=8, d=32, SR=2 -> N'=1024 (32x32).
//
// Round 12: software-pipeline ALL GEMM bodies (qconv / kv / proj) the same
// way the verified attn kernel is: 1 barrier per K-iter, register prefetch
// of tile t+1, LDS double-buffer. Attention kernel unchanged from R11.

typedef __attribute__((ext_vector_type(8))) short bf16x8;
typedef __attribute__((ext_vector_type(8))) unsigned short u16x8;
typedef __attribute__((ext_vector_type(4))) float f32x4;
typedef __attribute__((ext_vector_type(16))) float f32x16;
typedef __attribute__((ext_vector_type(2))) unsigned u32x2v;
typedef __attribute__((ext_vector_type(4))) unsigned u32x4v;

__device__ inline unsigned short f2bf(float f) {
  unsigned u = __float_as_uint(f);
  u += 0x7fffu + ((u >> 16) & 1u);
  return (unsigned short)(u >> 16);
}

__device__ inline u16x8 cast8(float4 a, float4 b) {
  u16x8 r;
  r[0] = f2bf(a.x); r[1] = f2bf(a.y); r[2] = f2bf(a.z); r[3] = f2bf(a.w);
  r[4] = f2bf(b.x); r[5] = f2bf(b.y); r[6] = f2bf(b.z); r[7] = f2bf(b.w);
  return r;
}

// ---------------------------------------------------------------------------
// prep: permute sr_w [256 o][256 ci][4 tap] f32 -> [256 o][4 tap][256 ci] bf16.
__global__ __launch_bounds__(256) void prep_kernel(
    const float* __restrict__ srw, unsigned short* __restrict__ srw_bf) {
  const int o = blockIdx.x, t = threadIdx.x;
  float4 v = reinterpret_cast<const float4*>(srw + (size_t)o * 1024)[t];
  srw_bf[(size_t)o * 1024 + 0 * 256 + t] = f2bf(v.x);
  srw_bf[(size_t)o * 1024 + 1 * 256 + t] = f2bf(v.y);
  srw_bf[(size_t)o * 1024 + 2 * 256 + t] = f2bf(v.z);
  srw_bf[(size_t)o * 1024 + 3 * 256 + t] = f2bf(v.w);
}

// ---------------------------------------------------------------------------
// q GEMM body, PIPELINED: C[M,N]bf16 = (A f32->bf16 @ W f32->bf16 ^T)*oscale.
// 128x64 tile, BK=32, 8 iters, LDS dbuf.
__device__ __forceinline__ void gemm_body_q(
    const float* __restrict__ Af, const float* __restrict__ W,
    unsigned short* __restrict__ C, float oscale,
    int m0, int n0, unsigned short* Asb, unsigned short* Bsb) {
  const int K = 256, N = 256, NK = 8;
  const int tid = threadIdx.x;
  const int w = tid >> 6, l = tid & 63, c = l & 15, g = l >> 4;
  const int wr = w >> 1, wc = w & 1;
  const int ar = tid >> 1, ah = tid & 1;
  const int bn = tid >> 2, bq = tid & 3;
  const int ABUF = 128 * 40, BBUF = 64 * 40;

  const float* aptr = Af + (size_t)(m0 + ar) * K + ah * 16;
  const float* wptr = W + (size_t)(n0 + bn) * K + bq * 8;

  f32x4 acc[4][2];
#pragma unroll
  for (int mt = 0; mt < 4; ++mt)
#pragma unroll
    for (int nt = 0; nt < 2; ++nt)
#pragma unroll
      for (int r = 0; r < 4; ++r) acc[mt][nt][r] = 0.f;

  // prologue: tile 0 -> buf 0
  {
    float4 a0 = *reinterpret_cast<const float4*>(aptr);
    float4 a1 = *reinterpret_cast<const float4*>(aptr + 4);
    float4 a2 = *reinterpret_cast<const float4*>(aptr + 8);
    float4 a3 = *reinterpret_cast<const float4*>(aptr + 12);
    float4 w0 = *reinterpret_cast<const float4*>(wptr);
    float4 w1 = *reinterpret_cast<const float4*>(wptr + 4);
    *reinterpret_cast<u16x8*>(&Asb[ar * 40 + ah * 16]) = cast8(a0, a1);
    *reinterpret_cast<u16x8*>(&Asb[ar * 40 + ah * 16 + 8]) = cast8(a2, a3);
    *reinterpret_cast<u16x8*>(&Bsb[bn * 40 + bq * 8]) = cast8(w0, w1);
  }

  for (int t = 0; t < NK; ++t) {
    const int cur = t & 1;
    __syncthreads();
    float4 na0, na1, na2, na3, nw0, nw1;
    if (t < NK - 1) {
      const float* ap = aptr + (t + 1) * 32;
      na0 = *reinterpret_cast<const float4*>(ap);
      na1 = *reinterpret_cast<const float4*>(ap + 4);
      na2 = *reinterpret_cast<const float4*>(ap + 8);
      na3 = *reinterpret_cast<const float4*>(ap + 12);
      const float* wp = wptr + (t + 1) * 32;
      nw0 = *reinterpret_cast<const float4*>(wp);
      nw1 = *reinterpret_cast<const float4*>(wp + 4);
    }
    bf16x8 af[4], bfr[2];
#pragma unroll
    for (int mt = 0; mt < 4; ++mt)
      af[mt] = *reinterpret_cast<const bf16x8*>(
          &Asb[cur * ABUF + (wr * 64 + mt * 16 + c) * 40 + g * 8]);
#pragma unroll
    for (int nt = 0; nt < 2; ++nt)
      bfr[nt] = *reinterpret_cast<const bf16x8*>(
          &Bsb[cur * BBUF + (wc * 32 + nt * 16 + c) * 40 + g * 8]);
#pragma unroll
    for (int mt = 0; mt < 4; ++mt)
#pragma unroll
      for (int nt = 0; nt < 2; ++nt)
        acc[mt][nt] = __builtin_amdgcn_mfma_f32_16x16x32_bf16(
            af[mt], bfr[nt], acc[mt][nt], 0, 0, 0);
    if (t < NK - 1) {
      const int nxt = cur ^ 1;
      *reinterpret_cast<u16x8*>(&Asb[nxt * ABUF + ar * 40 + ah * 16]) = cast8(na0, na1);
      *reinterpret_cast<u16x8*>(&Asb[nxt * ABUF + ar * 40 + ah * 16 + 8]) = cast8(na2, na3);
      *reinterpret_cast<u16x8*>(&Bsb[nxt * BBUF + bn * 40 + bq * 8]) = cast8(nw0, nw1);
    }
  }

#pragma unroll
  for (int mt = 0; mt < 4; ++mt)
#pragma unroll
    for (int nt = 0; nt < 2; ++nt) {
      int row = m0 + wr * 64 + mt * 16 + g * 4;
      int col = n0 + wc * 32 + nt * 16 + c;
#pragma unroll
      for (int r = 0; r < 4; ++r)
        C[(size_t)(row + r) * N + col] = f2bf(acc[mt][nt][r] * oscale);
    }
}

// ---------------------------------------------------------------------------
// Conv body, PIPELINED: 64x64 tile, tap-major K=1024, 32 iters, LDS dbuf.
__device__ __forceinline__ void conv_body(
    const float* __restrict__ Xf, const unsigned short* __restrict__ Wp,
    const float* __restrict__ bias, float* __restrict__ C,
    int m0, int n0, unsigned short* Asb, unsigned short* Bsb) {
  const int NK = 32;
  const int tid = threadIdx.x;
  const int w = tid >> 6, l = tid & 63, c = l & 15, g = l >> 4;
  const int wr = w >> 1, wc = w & 1;
  const int sr = tid >> 2, sh = tid & 3;
  const int BUF = 64 * 40;

  int base[4];
  {
    int row = m0 + sr;
    int b = row >> 10, o = row & 1023, oh = o >> 5, ow = o & 31;
#pragma unroll
    for (int tap = 0; tap < 4; ++tap) {
      int n = ((oh << 1) + (tap >> 1)) * 64 + (ow << 1) + (tap & 1);
      base[tap] = ((b << 12) + n) << 8;
    }
  }
  const unsigned short* wptr = Wp + (size_t)(n0 + sr) * 1024 + sh * 8;

  f32x4 acc[2][2];
#pragma unroll
  for (int mt = 0; mt < 2; ++mt)
#pragma unroll
    for (int nt = 0; nt < 2; ++nt)
#pragma unroll
      for (int r = 0; r < 4; ++r) acc[mt][nt][r] = 0.f;

  // prologue: tile 0 -> buf 0
  {
    const float* xp = Xf + base[0] + sh * 8;
    float4 a0 = *reinterpret_cast<const float4*>(xp);
    float4 a1 = *reinterpret_cast<const float4*>(xp + 4);
    *reinterpret_cast<u16x8*>(&Asb[sr * 40 + sh * 8]) = cast8(a0, a1);
    *reinterpret_cast<u16x8*>(&Bsb[sr * 40 + sh * 8]) =
        *reinterpret_cast<const u16x8*>(wptr);
  }

  for (int t = 0; t < NK; ++t) {
    const int cur = t & 1;
    __syncthreads();
    float4 na0, na1; u16x8 nw;
    if (t < NK - 1) {
      const int k0n = (t + 1) * 32;
      const float* xp = Xf + base[k0n >> 8] + (k0n & 255) + sh * 8;
      na0 = *reinterpret_cast<const float4*>(xp);
      na1 = *reinterpret_cast<const float4*>(xp + 4);
      nw = *reinterpret_cast<const u16x8*>(wptr + (t + 1) * 32);
    }
    bf16x8 af[2], bfr[2];
#pragma unroll
    for (int mt = 0; mt < 2; ++mt)
      af[mt] = *reinterpret_cast<const bf16x8*>(
          &Asb[cur * BUF + (wr * 32 + mt * 16 + c) * 40 + g * 8]);
#pragma unroll
    for (int nt = 0; nt < 2; ++nt)
      bfr[nt] = *reinterpret_cast<const bf16x8*>(
          &Bsb[cur * BUF + (wc * 32 + nt * 16 + c) * 40 + g * 8]);
#pragma unroll
    for (int mt = 0; mt < 2; ++mt)
#pragma unroll
      for (int nt = 0; nt < 2; ++nt)
        acc[mt][nt] = __builtin_amdgcn_mfma_f32_16x16x32_bf16(
            af[mt], bfr[nt], acc[mt][nt], 0, 0, 0);
    if (t < NK - 1) {
      const int nxt = cur ^ 1;
      *reinterpret_cast<u16x8*>(&Asb[nxt * BUF + sr * 40 + sh * 8]) = cast8(na0, na1);
      *reinterpret_cast<u16x8*>(&Bsb[nxt * BUF + sr * 40 + sh * 8]) = nw;
    }
  }

#pragma unroll
  for (int mt = 0; mt < 2; ++mt)
#pragma unroll
    for (int nt = 0; nt < 2; ++nt) {
      int row = m0 + wr * 32 + mt * 16 + g * 4;
      int col = n0 + wc * 32 + nt * 16 + c;
      float bv = bias[col];
#pragma unroll
      for (int r = 0; r < 4; ++r)
        C[(size_t)(row + r) * 256 + col] = acc[mt][nt][r] + bv;
    }
}

// ---------------------------------------------------------------------------
// Fused dispatch: blocks [0,512) = q GEMM, blocks [512,768) = conv.
__global__ __launch_bounds__(256) void qconv_kernel(
    const float* __restrict__ x, const float* __restrict__ q_w,
    unsigned short* __restrict__ q_bf, const unsigned short* __restrict__ srw_bf,
    const float* __restrict__ sr_b, float* __restrict__ xred, float qscale) {
  __shared__ unsigned short smem[2 * 128 * 40 + 2 * 64 * 40];
  const int bid = blockIdx.x;
  if (bid < 512) {
    gemm_body_q(x, q_w, q_bf, qscale,
                (bid >> 2) * 128, (bid & 3) * 64, smem, smem + 2 * 128 * 40);
  } else {
    int cb = bid - 512;
    conv_body(x, srw_bf, sr_b, xred,
              (cb >> 2) * 64, (cb & 3) * 64, smem, smem + 2 * 64 * 40);
  }
}

// ---------------------------------------------------------------------------
// kv GEMM, PIPELINED: 128x64 tile, 8 iters; epilogue K row-major + V^T.
__global__ __launch_bounds__(256) void kv_gemm(
    const unsigned short* __restrict__ A, const float* __restrict__ W,
    unsigned short* __restrict__ Kb, unsigned short* __restrict__ Vtp) {
  __shared__ unsigned short Asb[2 * 128 * 40];
  __shared__ unsigned short Bsb[2 * 64 * 40];
  const int K = 256, NK = 8;
  const int tid = threadIdx.x;
  const int w = tid >> 6, l = tid & 63, c = l & 15, g = l >> 4;
  const int wr = w >> 1, wc = w & 1;
  const int m0 = blockIdx.y * 128, n0 = blockIdx.x * 64;
  const int ar = tid >> 1, ah = tid & 1;
  const int bn = tid >> 2, bq = tid & 3;
  const int ABUF = 128 * 40, BBUF = 64 * 40;

  const unsigned short* aptr = A + (size_t)(m0 + ar) * K + ah * 16;
  const float* wptr = W + (size_t)(n0 + bn) * K + bq * 8;

  f32x4 acc[4][2];
#pragma unroll
  for (int mt = 0; mt < 4; ++mt)
#pragma unroll
    for (int nt = 0; nt < 2; ++nt)
#pragma unroll
      for (int r = 0; r < 4; ++r) acc[mt][nt][r] = 0.f;

  {
    u16x8 a0 = *reinterpret_cast<const u16x8*>(aptr);
    u16x8 a1 = *reinterpret_cast<const u16x8*>(aptr + 8);
    float4 w0 = *reinterpret_cast<const float4*>(wptr);
    float4 w1 = *reinterpret_cast<const float4*>(wptr + 4);
    *reinterpret_cast<u16x8*>(&Asb[ar * 40 + ah * 16]) = a0;
    *reinterpret_cast<u16x8*>(&Asb[ar * 40 + ah * 16 + 8]) = a1;
    *reinterpret_cast<u16x8*>(&Bsb[bn * 40 + bq * 8]) = cast8(w0, w1);
  }

  for (int t = 0; t < NK; ++t) {
    const int cur = t & 1;
    __syncthreads();
    u16x8 na0, na1; float4 nw0, nw1;
    if (t < NK - 1) {
      const unsigned short* ap = aptr + (t + 1) * 32;
      na0 = *reinterpret_cast<const u16x8*>(ap);
      na1 = *reinterpret_cast<const u16x8*>(ap + 8);
      const float* wp = wptr + (t + 1) * 32;
      nw0 = *reinterpret_cast<const float4*>(wp);
      nw1 = *reinterpret_cast<const float4*>(wp + 4);
    }
    bf16x8 af[4], bfr[2];
#pragma unroll
    for (int mt = 0; mt < 4; ++mt)
      af[mt] = *reinterpret_cast<const bf16x8*>(
          &Asb[cur * ABUF + (wr * 64 + mt * 16 + c) * 40 + g * 8]);
#pragma unroll
    for (int nt = 0; nt < 2; ++nt)
      bfr[nt] = *reinterpret_cast<const bf16x8*>(
          &Bsb[cur * BBUF + (wc * 32 + nt * 16 + c) * 40 + g * 8]);
#pragma unroll
    for (int mt = 0; mt < 4; ++mt)
#pragma unroll
      for (int nt = 0; nt < 2; ++nt)
        acc[mt][nt] = __builtin_amdgcn_mfma_f32_16x16x32_bf16(
            af[mt], bfr[nt], acc[mt][nt], 0, 0, 0);
    if (t < NK - 1) {
      const int nxt = cur ^ 1;
      *reinterpret_cast<u16x8*>(&Asb[nxt * ABUF + ar * 40 + ah * 16]) = na0;
      *reinterpret_cast<u16x8*>(&Asb[nxt * ABUF + ar * 40 + ah * 16 + 8]) = na1;
      *reinterpret_cast<u16x8*>(&Bsb[nxt * BBUF + bn * 40 + bq * 8]) = cast8(nw0, nw1);
    }
  }

#pragma unroll
  for (int mt = 0; mt < 4; ++mt)
#pragma unroll
    for (int nt = 0; nt < 2; ++nt) {
      int row = m0 + wr * 64 + mt * 16 + g * 4;
      int col = n0 + wc * 32 + nt * 16 + c;
#pragma unroll
      for (int r = 0; r < 4; ++r) {
        float v = acc[mt][nt][r];
        if (col < 256) {
          Kb[(size_t)(row + r) * 256 + col] = f2bf(v);
        } else {
          int head = (col - 256) >> 5, d = (col - 256) & 31;
          int rr = row + r;
          Vtp[((size_t)(((rr >> 10) << 3) + head) * 32 + d) * 1024 +
              (rr & 1023)] = f2bf(v);
        }
      }
    }
}

// ---------------------------------------------------------------------------
// proj GEMM, PIPELINED: 64x64 tile, 8 iters, 1024 blocks.
__global__ __launch_bounds__(256) void proj_gemm(
    const unsigned short* __restrict__ A, const float* __restrict__ W,
    const float* __restrict__ bias, float* __restrict__ C) {
  __shared__ unsigned short Asb[2 * 64 * 40];
  __shared__ unsigned short Bsb[2 * 64 * 40];
  const int NK = 8;
  const int tid = threadIdx.x;
  const int w = tid >> 6, l = tid & 63, c = l & 15, g = l >> 4;
  const int wr = w >> 1, wc = w & 1;
  const int m0 = blockIdx.y * 64, n0 = blockIdx.x * 64;
  const int sr = tid >> 2, sh = tid & 3;
  const int BUF = 64 * 40;

  const unsigned short* aptr = A + (size_t)(m0 + sr) * 256 + sh * 8;
  const float* wptr = W + (size_t)(n0 + sr) * 256 + sh * 8;

  f32x4 acc[2][2];
#pragma unroll
  for (int mt = 0; mt < 2; ++mt)
#pragma unroll
    for (int nt = 0; nt < 2; ++nt)
#pragma unroll
      for (int r = 0; r < 4; ++r) acc[mt][nt][r] = 0.f;

  {
    u16x8 av = *reinterpret_cast<const u16x8*>(aptr);
    float4 w0 = *reinterpret_cast<const float4*>(wptr);
    float4 w1 = *reinterpret_cast<const float4*>(wptr + 4);
    *reinterpret_cast<u16x8*>(&Asb[sr * 40 + sh * 8]) = av;
    *reinterpret_cast<u16x8*>(&Bsb[sr * 40 + sh * 8]) = cast8(w0, w1);
  }

  for (int t = 0; t < NK; ++t) {
    const int cur = t & 1;
    __syncthreads();
    u16x8 na; float4 nw0, nw1;
    if (t < NK - 1) {
      na = *reinterpret_cast<const u16x8*>(aptr + (t + 1) * 32);
      const float* wp = wptr + (t + 1) * 32;
      nw0 = *reinterpret_cast<const float4*>(wp);
      nw1 = *reinterpret_cast<const float4*>(wp + 4);
    }
    bf16x8 af[2], bfr[2];
#pragma unroll
    for (int mt = 0; mt < 2; ++mt)
      af[mt] = *reinterpret_cast<const bf16x8*>(
          &Asb[cur * BUF + (wr * 32 + mt * 16 + c) * 40 + g * 8]);
#pragma unroll
    for (int nt = 0; nt < 2; ++nt)
      bfr[nt] = *reinterpret_cast<const bf16x8*>(
          &Bsb[cur * BUF + (wc * 32 + nt * 16 + c) * 40 + g * 8]);
#pragma unroll
    for (int mt = 0; mt < 2; ++mt)
#pragma unroll
      for (int nt = 0; nt < 2; ++nt)
        acc[mt][nt] = __builtin_amdgcn_mfma_f32_16x16x32_bf16(
            af[mt], bfr[nt], acc[mt][nt], 0, 0, 0);
    if (t < NK - 1) {
      const int nxt = cur ^ 1;
      *reinterpret_cast<u16x8*>(&Asb[nxt * BUF + sr * 40 + sh * 8]) = na;
      *reinterpret_cast<u16x8*>(&Bsb[nxt * BUF + sr * 40 + sh * 8]) = cast8(nw0, nw1);
    }
  }

#pragma unroll
  for (int mt = 0; mt < 2; ++mt)
#pragma unroll
    for (int nt = 0; nt < 2; ++nt) {
      int row = m0 + wr * 32 + mt * 16 + g * 4;
      int col = n0 + wc * 32 + nt * 16 + c;
      float bv = bias[col];
#pragma unroll
      for (int r = 0; r < 4; ++r)
        C[(size_t)(row + r) * 256 + col] = acc[mt][nt][r] + bv;
    }
}

// ---------------------------------------------------------------------------
// LayerNorm over C=256; one wave per row, float4 loads, no LDS/barrier.
__global__ __launch_bounds__(256) void ln_kernel(
    const float* __restrict__ xr, const float* __restrict__ gam,
    const float* __restrict__ bet, unsigned short* __restrict__ xo) {
  const int w = threadIdx.x >> 6, l = threadIdx.x & 63;
  const int row = blockIdx.x * 4 + w;
  float4 v = *reinterpret_cast<const float4*>(xr + (size_t)row * 256 + l * 4);
  float s = (v.x + v.y) + (v.z + v.w);
  float s2 = (v.x * v.x + v.y * v.y) + (v.z * v.z + v.w * v.w);
#pragma unroll
  for (int off = 32; off > 0; off >>= 1) {
    s  += __shfl_xor(s, off, 64);
    s2 += __shfl_xor(s2, off, 64);
  }
  float mean = s * (1.f / 256.f);
  float var = s2 * (1.f / 256.f) - mean * mean;
  float rstd = rsqrtf(var + 1e-5f);
  float4 g = *reinterpret_cast<const float4*>(gam + l * 4);
  float4 bb = *reinterpret_cast<const float4*>(bet + l * 4);
  unsigned short o0 = f2bf((v.x - mean) * rstd * g.x + bb.x);
  unsigned short o1 = f2bf((v.y - mean) * rstd * g.y + bb.y);
  unsigned short o2 = f2bf((v.z - mean) * rstd * g.z + bb.z);
  unsigned short o3 = f2bf((v.w - mean) * rstd * g.w + bb.w);
  unsigned long long pk =
      (unsigned long long)o0 | ((unsigned long long)o1 << 16) |
      ((unsigned long long)o2 << 32) | ((unsigned long long)o3 << 48);
  *reinterpret_cast<unsigned long long*>(xo + (size_t)row * 256 + l * 4) = pk;
}

// ---------------------------------------------------------------------------
// 32x32x16-MFMA flash attention (verified R11). 4 waves/block, K+V LDS
// double-buffered, 1 barrier/tile, reg prefetch.
__global__ __launch_bounds__(256) void attn_mfma(
    const unsigned short* __restrict__ Qb,
    const unsigned short* __restrict__ Kb,
    const unsigned short* __restrict__ Vtg,
    unsigned short* __restrict__ O) {
  __shared__ __align__(16) unsigned short Kt[2][64][36];
  __shared__ __align__(16) unsigned short Vt[2][32][72];

  const int tid = threadIdx.x;
  const int l = tid & 63;
  const int w = tid >> 6;
  const int q32 = l & 31, hi = l >> 5;
  const int wg = blockIdx.x;
  const int qb = wg & 31, head = (wg >> 5) & 7, b = wg >> 8;
  const int hcol = head << 5;
  const int q0 = (b << 12) + (qb << 7) + (w << 5);

  bf16x8 qf[2];
  {
    const unsigned short* qp = Qb + (size_t)(q0 + q32) * 256 + hcol + hi * 8;
    qf[0] = *reinterpret_cast<const bf16x8*>(qp);
    qf[1] = *reinterpret_cast<const bf16x8*>(qp + 16);
  }

  const int sd = tid >> 3, skv = (tid & 7) << 3;
  const unsigned short* vtrow =
      Vtg + ((size_t)((b << 3) + head) * 32 + sd) * 1024 + skv;
  const int kr = tid >> 2, kh = (tid & 3) << 3;
  const unsigned short* ktrow =
      Kb + ((size_t)(b << 10) + kr) * 256 + hcol + kh;

  {
    u16x8 va = *reinterpret_cast<const u16x8*>(vtrow);
    *reinterpret_cast<u16x8*>(&Vt[0][sd][skv]) = va;
    u16x8 ka = *reinterpret_cast<const u16x8*>(ktrow);
    *reinterpret_cast<u16x8*>(&Kt[0][kr][kh]) = ka;
  }

  f32x16 acc;
#pragma unroll
  for (int r = 0; r < 16; ++r) acc[r] = 0.f;
  float lsum = 0.f;

  for (int t = 0; t < 16; ++t) {
    const int cur = t & 1;
    __syncthreads();

    u16x8 nv0, nk0;
    if (t < 15) {
      nv0 = *reinterpret_cast<const u16x8*>(vtrow + (t + 1) * 64);
      nk0 = *reinterpret_cast<const u16x8*>(ktrow + (size_t)(t + 1) * 64 * 256);
    }

    f32x16 s[2];
    {
      bf16x8 k00 = *reinterpret_cast<const bf16x8*>(&Kt[cur][q32][hi * 8]);
      bf16x8 k01 = *reinterpret_cast<const bf16x8*>(&Kt[cur][q32][hi * 8 + 16]);
      bf16x8 k10 = *reinterpret_cast<const bf16x8*>(&Kt[cur][q32 + 32][hi * 8]);
      bf16x8 k11 = *reinterpret_cast<const bf16x8*>(&Kt[cur][q32 + 32][hi * 8 + 16]);
      f32x16 z;
#pragma unroll
      for (int r = 0; r < 16; ++r) z[r] = 0.f;
      s[0] = __builtin_amdgcn_mfma_f32_32x32x16_bf16(k00, qf[0], z, 0, 0, 0);
      s[0] = __builtin_amdgcn_mfma_f32_32x32x16_bf16(k01, qf[1], s[0], 0, 0, 0);
      s[1] = __builtin_amdgcn_mfma_f32_32x32x16_bf16(k10, qf[0], z, 0, 0, 0);
      s[1] = __builtin_amdgcn_mfma_f32_32x32x16_bf16(k11, qf[1], s[1], 0, 0, 0);
    }

#pragma unroll
    for (int kvb = 0; kvb < 2; ++kvb) {
      float p16[16];
#pragma unroll
      for (int r = 0; r < 16; ++r)
        p16[r] = __builtin_amdgcn_exp2f(s[kvb][r]);
      float s0 = (p16[0] + p16[1]) + (p16[2] + p16[3]);
      float s1 = (p16[4] + p16[5]) + (p16[6] + p16[7]);
      float s2 = (p16[8] + p16[9]) + (p16[10] + p16[11]);
      float s3 = (p16[12] + p16[13]) + (p16[14] + p16[15]);
      lsum += (s0 + s1) + (s2 + s3);
      unsigned A[8];
#pragma unroll
      for (int i = 0; i < 8; ++i) {
        unsigned o;
        asm("v_cvt_pk_bf16_f32 %0, %1, %2"
            : "=v"(o) : "v"(p16[2 * i]), "v"(p16[2 * i + 1]));
        A[i] = o;
      }
      u32x2v r02 = __builtin_amdgcn_permlane32_swap(A[0], A[2], false, false);
      u32x2v r13 = __builtin_amdgcn_permlane32_swap(A[1], A[3], false, false);
      u32x2v r46 = __builtin_amdgcn_permlane32_swap(A[4], A[6], false, false);
      u32x2v r57 = __builtin_amdgcn_permlane32_swap(A[5], A[7], false, false);
      u32x4v pk0 = {r02[0], r13[0], r02[1], r13[1]};
      u32x4v pk1 = {r46[0], r57[0], r46[1], r57[1]};
      bf16x8 pf0 = __builtin_bit_cast(bf16x8, pk0);
      bf16x8 pf1 = __builtin_bit_cast(bf16x8, pk1);
      const unsigned short* vrow = &Vt[cur][q32][kvb * 32 + hi * 8];
      bf16x8 vf0 = *reinterpret_cast<const bf16x8*>(vrow);
      bf16x8 vf1 = *reinterpret_cast<const bf16x8*>(vrow + 16);
      acc = __builtin_amdgcn_mfma_f32_32x32x16_bf16(vf0, pf0, acc, 0, 0, 0);
      acc = __builtin_amdgcn_mfma_f32_32x32x16_bf16(vf1, pf1, acc, 0, 0, 0);
    }

    if (t < 15) {
      *reinterpret_cast<u16x8*>(&Vt[cur ^ 1][sd][skv]) = nv0;
      *reinterpret_cast<u16x8*>(&Kt[cur ^ 1][kr][kh]) = nk0;
    }
  }

  lsum += __shfl_xor(lsum, 32, 64);
  float inv = 1.f / lsum;
  unsigned short* orow = O + (size_t)(q0 + q32) * 256 + hcol;
#pragma unroll
  for (int rb = 0; rb < 4; ++rb) {
    const int d0 = rb * 8 + hi * 4;
    float a0 = acc[rb * 4 + 0] * inv, a1 = acc[rb * 4 + 1] * inv;
    float a2 = acc[rb * 4 + 2] * inv, a3 = acc[rb * 4 + 3] * inv;
    unsigned w0, w1;
    asm("v_cvt_pk_bf16_f32 %0, %1, %2" : "=v"(w0) : "v"(a0), "v"(a1));
    asm("v_cvt_pk_bf16_f32 %0, %1, %2" : "=v"(w1) : "v"(a2), "v"(a3));
    unsigned long long pk = (unsigned long long)w0 | ((unsigned long long)w1 << 32);
    *reinterpret_cast<unsigned long long*>(orow + d0) = pk;
  }
}

// ---------------------------------------------------------------------------
extern "C" void kernel_launch(void* const* d_in, const int* in_sizes, int n_in,
                              void* d_out, int out_size, void* d_ws,
                              size_t ws_size, hipStream_t stream) {
  const float* x      = (const float*)d_in[0];
  const float* sr_w   = (const float*)d_in[3];
  const float* sr_b   = (const float*)d_in[4];
  const float* ln_g   = (const float*)d_in[5];
  const float* ln_b   = (const float*)d_in[6];
  const float* q_w    = (const float*)d_in[7];
  const float* kv_w   = (const float*)d_in[8];
  const float* proj_w = (const float*)d_in[9];
  const float* proj_b = (const float*)d_in[10];
  float* out = (float*)d_out;

  char* ws = (char*)d_ws;
  unsigned short* q_bf    = (unsigned short*)(ws);               // 8 MB
  unsigned short* srw_bf  = (unsigned short*)(ws + 8388608);     // 512 KB
  float*          xred    = (float*)(ws + 8912896);              // 4 MB
  unsigned short* x_ln    = (unsigned short*)(ws + 13107200);    // 2 MB
  unsigned short* k_buf   = (unsigned short*)(ws + 15204352);    // 2 MB
  unsigned short* vt_buf  = (unsigned short*)(ws + 17301504);    // 2 MB
  unsigned short* attn_bf = (unsigned short*)(ws + 19398656);    // 8 MB

  const float qscale = 0.25506975154985854f;  // (1/sqrt(32)) * log2(e)

  // 1. prep: sr_w permute
  prep_kernel<<<256, 256, 0, stream>>>(sr_w, srw_bf);
  // 2. fused q GEMM (512 blocks) + conv (256 blocks), pipelined
  qconv_kernel<<<768, 256, 0, stream>>>(
      x, q_w, q_bf, srw_bf, sr_b, xred, qscale);
  // 3. LayerNorm (bf16 out), 1 wave/row
  ln_kernel<<<1024, 256, 0, stream>>>(xred, ln_g, ln_b, x_ln);
  // 4. kv = x_ln @ kv_w^T -> K row-major + V transposed, pipelined
  kv_gemm<<<dim3(8, 32), 256, 0, stream>>>(x_ln, kv_w, k_buf, vt_buf);
  // 5. attention (bf16 out), 4-wave blocks, K+V LDS double-buffered
  attn_mfma<<<1024, 256, 0, stream>>>(q_bf, k_buf, vt_buf, attn_bf);
  // 6. out = attn_o @ proj_w^T + proj_b (f32), pipelined, 1024 blocks
  proj_gemm<<<dim3(4, 256), 256, 0, stream>>>(attn_bf, proj_w, proj_b, out);
}